// Round 4
// baseline (1438.515 us; speedup 1.0000x reference)
//
#include <hip/hip_runtime.h>
#include <hip/hip_fp16.h>

#define NTOT (1u<<20)   // nodes total
#define ETOT (1u<<24)   // edges total
#define NG   256        // graphs
#define NPG  4096       // nodes per graph
#define EPG  65536      // edges per graph

// ---------------- workspace layout (in 4-byte words) ----------------
constexpr size_t W_OFF  = 0;                       // (NTOT+64) ints: CSR row offsets (global positions)
constexpr size_t W_DEG2 = W_OFF + NTOT + 64;       // NTOT float2: (indeg, outdeg)
constexpr size_t W_SRT  = W_DEG2 + 2*(size_t)NTOT; // ETOT ushorts = ETOT/2 words: sorted local src ids
constexpr size_t W_HA   = W_SRT + ETOT/2;          // NTOT*12 f32
constexpr size_t W_HB   = W_HA + (size_t)NTOT*12;  // NTOT*12 f32
constexpr size_t W_GSUM = W_HB + (size_t)NTOT*12;  // 256*4 f32
constexpr size_t W_SEQ  = W_GSUM + 1024;           // 256*32 f32
constexpr size_t W_PG   = W_SEQ + 8192;            // 256*1024 f32 pregates
constexpr size_t W_W16  = W_PG + 262144;           // 131072 words: W_hh as f16 pairs, transposed [128][1024]

// ---------------- per-graph counting sort (CSR by dst), scatter staged in LDS ----------------
// LDS: [0,16K) cur | [16K,20K) bscan | [20K,148K) region C = hd[16K]+hs[16K], reused as slds[128K]
#define SORT_LDS_BYTES (16384 + 4096 + 131072)
__global__ __launch_bounds__(1024) void k_sort(const int* __restrict__ esrc,
                                               const int* __restrict__ edst,
                                               int* __restrict__ off,
                                               float2* __restrict__ deg2,
                                               unsigned short* __restrict__ srt) {
  extern __shared__ char sm[];
  int* cur   = (int*)sm;                   // [4096]
  int* bscan = (int*)(sm + 16384);         // [1024]
  int* hd    = (int*)(sm + 20480);         // [4096]
  int* hs    = (int*)(sm + 20480 + 16384); // [4096]
  unsigned short* slds = (unsigned short*)(sm + 20480);  // [65536], reuses hd/hs space
  const int g = blockIdx.x;
  const int t = threadIdx.x;
  const int ebase = g * EPG;
  const int nbase = g * NPG;
  for (int i = t; i < NPG; i += 1024) { hd[i] = 0; hs[i] = 0; }
  __syncthreads();
  for (int e = t; e < EPG; e += 1024) {
    int s = esrc[ebase + e] - nbase;
    int d = edst[ebase + e] - nbase;
    atomicAdd(&hs[s], 1);
    atomicAdd(&hd[d], 1);
  }
  __syncthreads();
  // exclusive scan of hd[4096]: 4 per thread + Hillis-Steele over 1024 chunk sums
  int a0 = hd[t*4+0], a1 = hd[t*4+1], a2 = hd[t*4+2], a3 = hd[t*4+3];
  int csum = a0 + a1 + a2 + a3;
  bscan[t] = csum;
  __syncthreads();
  for (int o = 1; o < 1024; o <<= 1) {
    int v = (t >= o) ? bscan[t - o] : 0;
    __syncthreads();
    bscan[t] += v;
    __syncthreads();
  }
  int e0 = bscan[t] - csum;  // exclusive chunk offset
  cur[t*4+0] = e0;
  cur[t*4+1] = e0 + a0;
  cur[t*4+2] = e0 + a0 + a1;
  cur[t*4+3] = e0 + a0 + a1 + a2;
  __syncthreads();
  for (int i = t; i < NPG; i += 1024) {
    off[nbase + i] = ebase + cur[i];
    deg2[nbase + i] = make_float2((float)hd[i], (float)hs[i]);
  }
  if (g == NG - 1 && t == 0) off[NTOT] = (int)ETOT;
  __syncthreads();   // hd/hs fully consumed; region C becomes slds
  // scatter pass into LDS: place src into dst bucket
  for (int e = t; e < EPG; e += 1024) {
    int s = esrc[ebase + e] - nbase;
    int d = edst[ebase + e] - nbase;
    int p = atomicAdd(&cur[d], 1);
    slds[p] = (unsigned short)s;
  }
  __syncthreads();
  // coalesced stream-out: 128KB as 8192 x uint4
  uint4* dstv = (uint4*)(srt + (size_t)ebase);
  const uint4* srcv = (const uint4*)slds;
  for (int i = t; i < 8192; i += 1024)
    dstv[i] = srcv[i];
}

// ---------------- graph conv: aggregate in-edges, then linear+relu ----------------
// grid = 4096 blocks (16 per graph, 1 node/thread), XCD-swizzled: all blocks of a
// graph share blockIdx%8 -> same XCD L2 (round-robin dispatch heuristic).
template<int FIN, int FOUT, bool DEGIN, bool POOL>
__global__ __launch_bounds__(256) void k_conv(const int* __restrict__ off,
                                              const unsigned short* __restrict__ srt,
                                              const float* __restrict__ hin,
                                              const float* __restrict__ W,
                                              const float* __restrict__ Bv,
                                              float* __restrict__ hout,
                                              float* __restrict__ gsum) {
  __shared__ float wsm[FOUT*FIN + FOUT];
  __shared__ float4 red[POOL ? 256 : 1];
  const int b = blockIdx.x;
  const int t = threadIdx.x;
  const int xcd = b & 7, slot = b >> 3;
  const int part = slot & 15, gidx = slot >> 4;   // 16 parts/graph, 32 graphs/XCD
  const int g = xcd + 8 * gidx;
  for (int i = t; i < FOUT*FIN + FOUT; i += 256)
    wsm[i] = (i < FOUT*FIN) ? W[i] : Bv[i - FOUT*FIN];
  __syncthreads();
  const int nbase = g * NPG;
  const int n = nbase + part * 256 + t;
  const int e0 = off[n], e1 = off[n + 1];
  float acc[FIN];
  #pragma unroll
  for (int j = 0; j < FIN; j++) acc[j] = 0.f;
  #pragma unroll 4
  for (int e = e0; e < e1; e++) {
    const int s = nbase + (int)srt[e];
    if constexpr (DEGIN) {
      float2 v = ((const float2*)hin)[s];
      acc[0] += v.x; acc[1] += v.y;
    } else {
      const float4* r = (const float4*)(hin + (size_t)s * 12);
      float4 v0 = r[0], v1 = r[1], v2 = r[2];
      acc[0] += v0.x; acc[1] += v0.y; acc[2]  += v0.z; acc[3]  += v0.w;
      acc[4] += v1.x; acc[5] += v1.y; acc[6]  += v1.z; acc[7]  += v1.w;
      acc[8] += v2.x; acc[9] += v2.y; acc[10] += v2.z; acc[11] += v2.w;
    }
  }
  float o[FOUT];
  #pragma unroll
  for (int j = 0; j < FOUT; j++) {
    float v = wsm[FOUT*FIN + j];
    #pragma unroll
    for (int kk = 0; kk < FIN; kk++) v += wsm[j*FIN + kk] * acc[kk];
    o[j] = fmaxf(v, 0.f);
  }
  if constexpr (!POOL) {
    float4* wout = (float4*)(hout + (size_t)n * 12);
    wout[0] = make_float4(o[0], o[1], o[2],  o[3]);
    wout[1] = make_float4(o[4], o[5], o[6],  o[7]);
    wout[2] = make_float4(o[8], o[9], o[10], o[11]);
  } else {
    red[t] = make_float4(o[0], o[1], o[2], o[3]);
    __syncthreads();
    for (int o2 = 128; o2 > 0; o2 >>= 1) {
      if (t < o2) {
        red[t].x += red[t + o2].x; red[t].y += red[t + o2].y;
        red[t].z += red[t + o2].z; red[t].w += red[t + o2].w;
      }
      __syncthreads();
    }
    if (t == 0) {
      atomicAdd(&gsum[g*4+0], red[0].x);
      atomicAdd(&gsum[g*4+1], red[0].y);
      atomicAdd(&gsum[g*4+2], red[0].z);
      atomicAdd(&gsum[g*4+3], red[0].w);
    }
  }
}

// ---------------- fc1 + concat -> seq [256][32] ----------------
__global__ __launch_bounds__(256) void k_small(const float* __restrict__ x,
                                               const float* __restrict__ fw,
                                               const float* __restrict__ fb,
                                               const float* __restrict__ gsum,
                                               float* __restrict__ seq) {
  const int t = threadIdx.x;  // graph / seq row
  float xv[64];
  #pragma unroll
  for (int k = 0; k < 64; k++) xv[k] = x[t*64 + k];
  for (int j = 0; j < 28; j++) {
    float acc = fb[j];
    #pragma unroll
    for (int k = 0; k < 64; k++) acc += fw[j*64 + k] * xv[k];
    seq[t*32 + j] = fmaxf(acc, 0.f);
  }
  #pragma unroll
  for (int f = 0; f < 4; f++)
    seq[t*32 + 28 + f] = gsum[t*4 + f] * (1.0f / 4096.0f);
}

// ---------------- input-side gates: pg[step][row] = b_ih+b_hh + W_ih@xt ----------------
__global__ __launch_bounds__(256) void k_pregates(const float* __restrict__ Wih,
                                                  const float* __restrict__ bih,
                                                  const float* __restrict__ bhh,
                                                  const float* __restrict__ seq,
                                                  float* __restrict__ pg) {
  const int b = blockIdx.x;
  const int step = b >> 2;
  const int row = (b & 3) * 256 + threadIdx.x;
  const float* sr = seq + step * 32;
  float acc = bih[row] + bhh[row];
  const float4* wr = (const float4*)(Wih + (size_t)row * 32);
  #pragma unroll
  for (int c = 0; c < 8; c++) {
    float4 w = wr[c];
    acc += w.x * sr[4*c+0] + w.y * sr[4*c+1] + w.z * sr[4*c+2] + w.w * sr[4*c+3];
  }
  pg[(size_t)step * 1024 + row] = acc;
}

// ---------------- W_hh f32 -> f16 pairs, transposed [pair j][row t] ----------------
__global__ __launch_bounds__(256) void k_w16(const float* __restrict__ Whh,
                                             unsigned int* __restrict__ w16) {
  const int p = blockIdx.x * 256 + threadIdx.x;   // 131072
  const int t = p >> 7, j = p & 127;
  float2 v = ((const float2*)Whh)[(size_t)t * 128 + j];
  __half2 h = __floats2half2_rn(v.x, v.y);
  w16[(size_t)j * 1024 + t] = *(unsigned int*)&h;
}

// ---------------- LSTM: single workgroup, 1024 thr x 1 row, spill-free 96/32 split ----------------
typedef _Float16 half2_t __attribute__((ext_vector_type(2)));

__device__ inline float dot2(unsigned int a, unsigned int b, float c) {
#if defined(__has_builtin) && __has_builtin(__builtin_amdgcn_fdot2)
  return __builtin_amdgcn_fdot2(__builtin_bit_cast(half2_t, a),
                                __builtin_bit_cast(half2_t, b), c, false);
#else
  __half2 ha = *(__half2*)&a, hb = *(__half2*)&b;
  float2 fa = __half22float2(ha), fb = __half22float2(hb);
  return c + fa.x * fb.x + fa.y * fb.y;
#endif
}

// 1024 threads, 1 gate-row each. 96 weight-pairs in VGPR (96 regs + ~22 working
// fits the 128-VGPR budget the allocator picks at 16 waves -> ZERO spill; rounds
// 2-3 proved the backend treats launch_bounds min-waves as a range and keeps
// choosing 128). Remaining 32 pairs/row in LDS: [1024 thr][8 uint4 slots],
// slot = c ^ (t&7) XOR swizzle (8 slots x 16B spans all 32 banks).
#define LSTM_WLDS_BYTES (1024*8*16)              // 131072
#define LSTM_GEX_OFF    LSTM_WLDS_BYTES
#define LSTM_HBUF_OFF   (LSTM_WLDS_BYTES + 4096)
#define LSTM_LDS_BYTES  (LSTM_WLDS_BYTES + 4096 + 512)

__device__ inline float fast_sig(float x) {
  return 1.f / (1.f + __expf(-x));
}
__device__ inline float fast_tanh(float x) {
  float xc = fminf(fmaxf(x, -30.f), 30.f);   // avoid inf/inf
  float e = __expf(2.f * xc);
  return (e - 1.f) / (e + 1.f);
}

__global__ void __launch_bounds__(1024)
k_lstm(const unsigned int* __restrict__ w16,
       const float* __restrict__ pg,
       float* __restrict__ out) {
  extern __shared__ char smem[];
  uint4* wlds = (uint4*)smem;
  float* gex = (float*)(smem + LSTM_GEX_OFF);                 // 1024 f32
  unsigned int* hbuf = (unsigned int*)(smem + LSTM_HBUF_OFF); // 128 uints = 256 f16
  const int t = threadIdx.x;          // owns gate-row t
  const int swz = t & 7;
  unsigned int wr[96];
  #pragma unroll
  for (int j = 0; j < 96; j++) wr[j] = w16[(size_t)j * 1024 + t];
  #pragma unroll
  for (int c = 0; c < 8; c++) {
    uint4 a;
    a.x = w16[(size_t)(96 + 4*c + 0) * 1024 + t];
    a.y = w16[(size_t)(96 + 4*c + 1) * 1024 + t];
    a.z = w16[(size_t)(96 + 4*c + 2) * 1024 + t];
    a.w = w16[(size_t)(96 + 4*c + 3) * 1024 + t];
    wlds[t * 8 + (c ^ swz)] = a;
  }
  if (t < 128) hbuf[t] = 0u;   // h0 = 0
  float cs = 0.f;              // c_state, live in threads t<256
  __syncthreads();
  const uint4* h4 = (const uint4*)hbuf;
  float p0 = pg[t];            // software-pipelined pregate load
  for (int step = 0; step < 256; ++step) {
    float n0 = 0.f;
    if (step < 255) n0 = pg[(size_t)(step + 1) * 1024 + t];
    // 4 independent accumulators break the dependent-FMA chain (32-deep each)
    float a0 = p0, a1 = 0.f, a2 = 0.f, a3 = 0.f;
    #pragma unroll
    for (int c = 0; c < 24; c++) {       // register-resident 96 pairs
      uint4 hh = h4[c];
      a0 = dot2(wr[4*c+0], hh.x, a0);
      a1 = dot2(wr[4*c+1], hh.y, a1);
      a2 = dot2(wr[4*c+2], hh.z, a2);
      a3 = dot2(wr[4*c+3], hh.w, a3);
    }
    #pragma unroll
    for (int c = 0; c < 8; c++) {        // LDS-resident 32 pairs
      uint4 hh = h4[24 + c];
      uint4 wv = wlds[t * 8 + (c ^ swz)];
      a0 = dot2(wv.x, hh.x, a0);
      a1 = dot2(wv.y, hh.y, a1);
      a2 = dot2(wv.z, hh.z, a2);
      a3 = dot2(wv.w, hh.w, a3);
    }
    gex[t] = (a0 + a1) + (a2 + a3);
    __syncthreads();
    if (t < 256) {
      float gi = gex[t], gf = gex[t + 256], gg = gex[t + 512], go = gex[t + 768];
      float si = fast_sig(gi);
      float sf = fast_sig(gf);
      float so = fast_sig(go);
      float tg = fast_tanh(gg);
      cs = sf * cs + si * tg;
      float hn = so * fast_tanh(cs);
      out[step * 256 + t] = hn;
      ((unsigned short*)hbuf)[t] = __half_as_ushort(__float2half(hn));
    }
    __syncthreads();
    p0 = n0;
  }
}

extern "C" void kernel_launch(void* const* d_in, const int* in_sizes, int n_in,
                              void* d_out, int out_size, void* d_ws, size_t ws_size,
                              hipStream_t stream) {
  const float* x    = (const float*)d_in[0];
  const int*   esrc = (const int*)d_in[1];
  const int*   edst = (const int*)d_in[2];
  // d_in[3] node_graph_ids: implied by node index (n >> 12)
  const float* fc1w = (const float*)d_in[4];
  const float* fc1b = (const float*)d_in[5];
  const float* g1w  = (const float*)d_in[6];
  const float* g1b  = (const float*)d_in[7];
  const float* g2w  = (const float*)d_in[8];
  const float* g2b  = (const float*)d_in[9];
  const float* g3w  = (const float*)d_in[10];
  const float* g3b  = (const float*)d_in[11];
  const float* Wih  = (const float*)d_in[12];
  const float* Whh  = (const float*)d_in[13];
  const float* bih  = (const float*)d_in[14];
  const float* bhh  = (const float*)d_in[15];
  // d_in[16], d_in[17]: w_omega/u_omega — result discarded by reference

  float* ws = (float*)d_ws;
  int*            off  = (int*)(ws + W_OFF);
  float*          deg2 = ws + W_DEG2;
  unsigned short* srt  = (unsigned short*)(ws + W_SRT);
  float*          ha   = ws + W_HA;
  float*          hb   = ws + W_HB;
  float*          gsum = ws + W_GSUM;
  float*          seq  = ws + W_SEQ;
  float*          pg   = ws + W_PG;
  unsigned int*   w16  = (unsigned int*)(ws + W_W16);

  hipMemsetAsync(gsum, 0, 1024 * 4, stream);
  k_sort<<<256, 1024, SORT_LDS_BYTES, stream>>>(esrc, edst, off, (float2*)deg2, srt);
  k_w16<<<512, 256, 0, stream>>>(Whh, w16);
  k_conv<2, 12, true,  false><<<4096, 256, 0, stream>>>(off, srt, deg2, g1w, g1b, ha, nullptr);
  k_conv<12, 12, false, false><<<4096, 256, 0, stream>>>(off, srt, ha, g2w, g2b, hb, nullptr);
  k_conv<12, 4, false, true ><<<4096, 256, 0, stream>>>(off, srt, hb, g3w, g3b, nullptr, gsum);
  k_small<<<1, 256, 0, stream>>>(x, fc1w, fc1b, gsum, seq);
  k_pregates<<<1024, 256, 0, stream>>>(Wih, bih, bhh, seq, pg);
  k_lstm<<<1, 1024, LSTM_LDS_BYTES, stream>>>(w16, pg, (float*)d_out);
}

// Round 5
// 1204.809 us; speedup vs baseline: 1.1940x; 1.1940x over previous
//
#include <hip/hip_runtime.h>
#include <hip/hip_fp16.h>

#define NTOT (1u<<20)   // nodes total
#define ETOT (1u<<24)   // edges total
#define NG   256        // graphs
#define NPG  4096       // nodes per graph
#define EPG  65536      // edges per graph

// ---------------- workspace layout (in 4-byte words) ----------------
constexpr size_t W_OFF  = 0;                       // (NTOT+64) ints: CSR row offsets (global positions)
constexpr size_t W_DEG2 = W_OFF + NTOT + 64;       // NTOT float2: (indeg, outdeg)
constexpr size_t W_SRT  = W_DEG2 + 2*(size_t)NTOT; // ETOT ushorts = ETOT/2 words: sorted local src ids
constexpr size_t W_HA   = W_SRT + ETOT/2;          // NTOT*12 f32
constexpr size_t W_HB   = W_HA + (size_t)NTOT*12;  // NTOT*12 f32
constexpr size_t W_GSUM = W_HB + (size_t)NTOT*12;  // 256*4 f32
constexpr size_t W_SEQ  = W_GSUM + 1024;           // 256*32 f32
constexpr size_t W_PG   = W_SEQ + 8192;            // 256*256*4 f32 pregates (float4 per (step,t))
constexpr size_t W_W16  = W_PG + 262144;           // 131072 words: W_hh f16 pairs, permuted (see k_w16)

// ---------------- per-graph counting sort (CSR by dst), scatter staged in LDS ----------------
// LDS: [0,16K) cur | [16K,20K) bscan | [20K,148K) region C = hd[16K]+hs[16K], reused as slds[128K]
#define SORT_LDS_BYTES (16384 + 4096 + 131072)
__global__ __launch_bounds__(1024) void k_sort(const int* __restrict__ esrc,
                                               const int* __restrict__ edst,
                                               int* __restrict__ off,
                                               float2* __restrict__ deg2,
                                               unsigned short* __restrict__ srt) {
  extern __shared__ char sm[];
  int* cur   = (int*)sm;                   // [4096]
  int* bscan = (int*)(sm + 16384);         // [1024]
  int* hd    = (int*)(sm + 20480);         // [4096]
  int* hs    = (int*)(sm + 20480 + 16384); // [4096]
  unsigned short* slds = (unsigned short*)(sm + 20480);  // [65536], reuses hd/hs space
  const int g = blockIdx.x;
  const int t = threadIdx.x;
  const int ebase = g * EPG;
  const int nbase = g * NPG;
  for (int i = t; i < NPG; i += 1024) { hd[i] = 0; hs[i] = 0; }
  __syncthreads();
  for (int e = t; e < EPG; e += 1024) {
    int s = esrc[ebase + e] - nbase;
    int d = edst[ebase + e] - nbase;
    atomicAdd(&hs[s], 1);
    atomicAdd(&hd[d], 1);
  }
  __syncthreads();
  // exclusive scan of hd[4096]: 4 per thread + Hillis-Steele over 1024 chunk sums
  int a0 = hd[t*4+0], a1 = hd[t*4+1], a2 = hd[t*4+2], a3 = hd[t*4+3];
  int csum = a0 + a1 + a2 + a3;
  bscan[t] = csum;
  __syncthreads();
  for (int o = 1; o < 1024; o <<= 1) {
    int v = (t >= o) ? bscan[t - o] : 0;
    __syncthreads();
    bscan[t] += v;
    __syncthreads();
  }
  int e0 = bscan[t] - csum;  // exclusive chunk offset
  cur[t*4+0] = e0;
  cur[t*4+1] = e0 + a0;
  cur[t*4+2] = e0 + a0 + a1;
  cur[t*4+3] = e0 + a0 + a1 + a2;
  __syncthreads();
  for (int i = t; i < NPG; i += 1024) {
    off[nbase + i] = ebase + cur[i];
    deg2[nbase + i] = make_float2((float)hd[i], (float)hs[i]);
  }
  if (g == NG - 1 && t == 0) off[NTOT] = (int)ETOT;
  __syncthreads();   // hd/hs fully consumed; region C becomes slds
  // scatter pass into LDS: place src into dst bucket
  for (int e = t; e < EPG; e += 1024) {
    int s = esrc[ebase + e] - nbase;
    int d = edst[ebase + e] - nbase;
    int p = atomicAdd(&cur[d], 1);
    slds[p] = (unsigned short)s;
  }
  __syncthreads();
  // coalesced stream-out: 128KB as 8192 x uint4
  uint4* dstv = (uint4*)(srt + (size_t)ebase);
  const uint4* srcv = (const uint4*)slds;
  for (int i = t; i < 8192; i += 1024)
    dstv[i] = srcv[i];
}

// ---------------- graph conv: aggregate in-edges, then linear+relu ----------------
template<int FIN, int FOUT, bool DEGIN, bool POOL>
__global__ __launch_bounds__(256) void k_conv(const int* __restrict__ off,
                                              const unsigned short* __restrict__ srt,
                                              const float* __restrict__ hin,
                                              const float* __restrict__ W,
                                              const float* __restrict__ Bv,
                                              float* __restrict__ hout,
                                              float* __restrict__ gsum) {
  __shared__ float wsm[FOUT*FIN + FOUT];
  __shared__ float4 red[POOL ? 256 : 1];
  const int b = blockIdx.x;
  const int t = threadIdx.x;
  const int xcd = b & 7, slot = b >> 3;
  const int part = slot & 15, gidx = slot >> 4;   // 16 parts/graph, 32 graphs/XCD
  const int g = xcd + 8 * gidx;
  for (int i = t; i < FOUT*FIN + FOUT; i += 256)
    wsm[i] = (i < FOUT*FIN) ? W[i] : Bv[i - FOUT*FIN];
  __syncthreads();
  const int nbase = g * NPG;
  const int n = nbase + part * 256 + t;
  const int e0 = off[n], e1 = off[n + 1];
  float acc[FIN];
  #pragma unroll
  for (int j = 0; j < FIN; j++) acc[j] = 0.f;
  #pragma unroll 4
  for (int e = e0; e < e1; e++) {
    const int s = nbase + (int)srt[e];
    if constexpr (DEGIN) {
      float2 v = ((const float2*)hin)[s];
      acc[0] += v.x; acc[1] += v.y;
    } else {
      const float4* r = (const float4*)(hin + (size_t)s * 12);
      float4 v0 = r[0], v1 = r[1], v2 = r[2];
      acc[0] += v0.x; acc[1] += v0.y; acc[2]  += v0.z; acc[3]  += v0.w;
      acc[4] += v1.x; acc[5] += v1.y; acc[6]  += v1.z; acc[7]  += v1.w;
      acc[8] += v2.x; acc[9] += v2.y; acc[10] += v2.z; acc[11] += v2.w;
    }
  }
  float o[FOUT];
  #pragma unroll
  for (int j = 0; j < FOUT; j++) {
    float v = wsm[FOUT*FIN + j];
    #pragma unroll
    for (int kk = 0; kk < FIN; kk++) v += wsm[j*FIN + kk] * acc[kk];
    o[j] = fmaxf(v, 0.f);
  }
  if constexpr (!POOL) {
    float4* wout = (float4*)(hout + (size_t)n * 12);
    wout[0] = make_float4(o[0], o[1], o[2],  o[3]);
    wout[1] = make_float4(o[4], o[5], o[6],  o[7]);
    wout[2] = make_float4(o[8], o[9], o[10], o[11]);
  } else {
    red[t] = make_float4(o[0], o[1], o[2], o[3]);
    __syncthreads();
    for (int o2 = 128; o2 > 0; o2 >>= 1) {
      if (t < o2) {
        red[t].x += red[t + o2].x; red[t].y += red[t + o2].y;
        red[t].z += red[t + o2].z; red[t].w += red[t + o2].w;
      }
      __syncthreads();
    }
    if (t == 0) {
      atomicAdd(&gsum[g*4+0], red[0].x);
      atomicAdd(&gsum[g*4+1], red[0].y);
      atomicAdd(&gsum[g*4+2], red[0].z);
      atomicAdd(&gsum[g*4+3], red[0].w);
    }
  }
}

// ---------------- fc1 + concat -> seq [256][32] ----------------
__global__ __launch_bounds__(256) void k_small(const float* __restrict__ x,
                                               const float* __restrict__ fw,
                                               const float* __restrict__ fb,
                                               const float* __restrict__ gsum,
                                               float* __restrict__ seq) {
  const int t = threadIdx.x;  // graph / seq row
  float xv[64];
  #pragma unroll
  for (int k = 0; k < 64; k++) xv[k] = x[t*64 + k];
  for (int j = 0; j < 28; j++) {
    float acc = fb[j];
    #pragma unroll
    for (int k = 0; k < 64; k++) acc += fw[j*64 + k] * xv[k];
    seq[t*32 + j] = fmaxf(acc, 0.f);
  }
  #pragma unroll
  for (int f = 0; f < 4; f++)
    seq[t*32 + 28 + f] = gsum[t*4 + f] * (1.0f / 4096.0f);
}

// ---------------- input-side gates, transposed: pg4[(step*256+rt)*4 + gate] ----------------
__global__ __launch_bounds__(256) void k_pregates(const float* __restrict__ Wih,
                                                  const float* __restrict__ bih,
                                                  const float* __restrict__ bhh,
                                                  const float* __restrict__ seq,
                                                  float* __restrict__ pg4) {
  const int b = blockIdx.x;
  const int step = b >> 2;
  const int gate = b & 3;
  const int rt = threadIdx.x;
  const int row = gate * 256 + rt;
  const float* sr = seq + step * 32;
  float acc = bih[row] + bhh[row];
  const float4* wr = (const float4*)(Wih + (size_t)row * 32);
  #pragma unroll
  for (int c = 0; c < 8; c++) {
    float4 w = wr[c];
    acc += w.x * sr[4*c+0] + w.y * sr[4*c+1] + w.z * sr[4*c+2] + w.w * sr[4*c+3];
  }
  pg4[((size_t)step * 256 + rt) * 4 + gate] = acc;
}

// ---------------- W_hh f32 -> f16 pairs, permuted for the DPP-GEMV layout ----------------
// Element w16[j*1024 + t], j=p*8+u, t=w*64+l (l=r*16+g):
//   = W_hh[row w*64+p*4+r][f16 cols 2c,2c+1], c = g*8+u.
__global__ __launch_bounds__(256) void k_w16(const float* __restrict__ Whh,
                                             unsigned int* __restrict__ w16) {
  const int pid = blockIdx.x * 256 + threadIdx.x;   // [0, 131072)
  const int j = pid >> 10, t = pid & 1023;
  const int p = j >> 3, u = j & 7;
  const int w = t >> 6, r = (t >> 4) & 3, g = t & 15;
  const int R = w * 64 + p * 4 + r;
  const int c = g * 8 + u;
  float2 v = ((const float2*)Whh)[(size_t)R * 128 + c];
  __half2 h = __floats2half2_rn(v.x, v.y);
  w16[pid] = *(unsigned int*)&h;
}

// ---------------- LSTM: single WG, lane-distributed K + DPP row reduction ----------------
typedef _Float16 half2_t __attribute__((ext_vector_type(2)));

__device__ inline float dot2(unsigned int a, unsigned int b, float c) {
  return __builtin_amdgcn_fdot2(__builtin_bit_cast(half2_t, a),
                                __builtin_bit_cast(half2_t, b), c, false);
}

// sum across each 16-lane row via DPP row_shr (lane l%16==15 holds the sum)
__device__ inline float red16(float v) {
  int x;
  x = __builtin_amdgcn_update_dpp(0, __builtin_bit_cast(int, v), 0x111, 0xF, 0xF, false);
  v += __builtin_bit_cast(float, x);
  x = __builtin_amdgcn_update_dpp(0, __builtin_bit_cast(int, v), 0x112, 0xF, 0xF, false);
  v += __builtin_bit_cast(float, x);
  x = __builtin_amdgcn_update_dpp(0, __builtin_bit_cast(int, v), 0x114, 0xF, 0xF, false);
  v += __builtin_bit_cast(float, x);
  x = __builtin_amdgcn_update_dpp(0, __builtin_bit_cast(int, v), 0x118, 0xF, 0xF, false);
  v += __builtin_bit_cast(float, x);
  return v;
}

__device__ inline float fast_sig(float x) { return 1.f / (1.f + __expf(-x)); }
__device__ inline float fast_tanh(float x) {
  float xc = fminf(fmaxf(x, -30.f), 30.f);
  float e = __expf(2.f * xc);
  return (e - 1.f) / (e + 1.f);
}

// LDS: [0, 147456) weights: per thread 36 words (32 weight uints passes 12-15 +
// 4 pad words; pads of threads 0..31 hold h as f16 pairs). [147456, 151552) gex.
#define LSTM_LDS_BYTES 151552

// Wave layout: lane l = r*16+g; thread owns rows w*64+p*4+r (p=0..15), K-slice
// f16 [g*16, g*16+16). 96 weight uints in VGPR, 32 in LDS. h lane-distributed;
// 16-lane DPP reduce per pass; results staged 4 passes -> one b128 gex store.
__global__ void __attribute__((amdgpu_flat_work_group_size(1024, 1024),
                               amdgpu_waves_per_eu(4, 4)))
k_lstm(const unsigned int* __restrict__ w16,
       const float* __restrict__ pg4,
       float* __restrict__ out) {
  extern __shared__ char smem[];
  unsigned int* wl = (unsigned int*)smem;
  float* gex = (float*)(smem + 147456);
  const int t = threadIdx.x;
  const int w = t >> 6, r = (t >> 4) & 3, g = t & 15;
  unsigned int wr[96];
  #pragma unroll
  for (int j = 0; j < 96; j++) wr[j] = w16[(size_t)j * 1024 + t];
  #pragma unroll
  for (int j = 96; j < 128; j += 4) {
    uint4 v;
    v.x = w16[(size_t)(j + 0) * 1024 + t];
    v.y = w16[(size_t)(j + 1) * 1024 + t];
    v.z = w16[(size_t)(j + 2) * 1024 + t];
    v.w = w16[(size_t)(j + 3) * 1024 + t];
    *(uint4*)(wl + t * 36 + (j - 96)) = v;
  }
  if (t < 128) wl[(t >> 2) * 36 + 32 + (t & 3)] = 0u;   // h0 = 0
  float cs = 0.f;
  __syncthreads();
  const int hbase = 2 * g * 36 + 32;
  const int gexb = (t >> 6) * 64 + (t & 3) * 16 + ((t & 63) >> 2);  // nonlin read base
  for (int step = 0; step < 256; ++step) {
    uint4 h0 = *(const uint4*)(wl + hbase);
    uint4 h1 = *(const uint4*)(wl + hbase + 36);
    float res[4];
    #pragma unroll
    for (int p = 0; p < 16; ++p) {
      float s0 = 0.f, s1 = 0.f;
      if (p < 12) {
        s0 = dot2(wr[p*8+0], h0.x, s0);
        s0 = dot2(wr[p*8+1], h0.y, s0);
        s0 = dot2(wr[p*8+2], h0.z, s0);
        s0 = dot2(wr[p*8+3], h0.w, s0);
        s1 = dot2(wr[p*8+4], h1.x, s1);
        s1 = dot2(wr[p*8+5], h1.y, s1);
        s1 = dot2(wr[p*8+6], h1.z, s1);
        s1 = dot2(wr[p*8+7], h1.w, s1);
      } else {
        uint4 wv0 = *(const uint4*)(wl + t * 36 + (p - 12) * 8);
        uint4 wv1 = *(const uint4*)(wl + t * 36 + (p - 12) * 8 + 4);
        s0 = dot2(wv0.x, h0.x, s0);
        s0 = dot2(wv0.y, h0.y, s0);
        s0 = dot2(wv0.z, h0.z, s0);
        s0 = dot2(wv0.w, h0.w, s0);
        s1 = dot2(wv1.x, h1.x, s1);
        s1 = dot2(wv1.y, h1.y, s1);
        s1 = dot2(wv1.z, h1.z, s1);
        s1 = dot2(wv1.w, h1.w, s1);
      }
      res[p & 3] = red16(s0 + s1);
      if ((p & 3) == 3) {
        if ((t & 15) == 15)
          *(float4*)(gex + w * 64 + r * 16 + (p - 3)) =
              make_float4(res[0], res[1], res[2], res[3]);
      }
    }
    __syncthreads();
    if (t < 256) {
      float4 pf = *(const float4*)(pg4 + ((size_t)step * 256 + t) * 4);
      // gate rows R = t + 256k; gex index = (R>>6)*64 + (q&3)*16 + (q>>2), q=R&63
      float gi = gex[gexb +   0] + pf.x;
      float gf = gex[gexb + 256] + pf.y;
      float gg = gex[gexb + 512] + pf.z;
      float go = gex[gexb + 768] + pf.w;
      float si = fast_sig(gi);
      float sf = fast_sig(gf);
      float so = fast_sig(go);
      float tg = fast_tanh(gg);
      cs = sf * cs + si * tg;
      float hn = so * fast_tanh(cs);
      out[step * 256 + t] = hn;
      ((unsigned short*)smem)[(((t >> 3) * 36 + 32 + ((t >> 1) & 3)) << 1) + (t & 1)] =
          __half_as_ushort(__float2half(hn));
    }
    __syncthreads();
  }
}

extern "C" void kernel_launch(void* const* d_in, const int* in_sizes, int n_in,
                              void* d_out, int out_size, void* d_ws, size_t ws_size,
                              hipStream_t stream) {
  const float* x    = (const float*)d_in[0];
  const int*   esrc = (const int*)d_in[1];
  const int*   edst = (const int*)d_in[2];
  // d_in[3] node_graph_ids: implied by node index (n >> 12)
  const float* fc1w = (const float*)d_in[4];
  const float* fc1b = (const float*)d_in[5];
  const float* g1w  = (const float*)d_in[6];
  const float* g1b  = (const float*)d_in[7];
  const float* g2w  = (const float*)d_in[8];
  const float* g2b  = (const float*)d_in[9];
  const float* g3w  = (const float*)d_in[10];
  const float* g3b  = (const float*)d_in[11];
  const float* Wih  = (const float*)d_in[12];
  const float* Whh  = (const float*)d_in[13];
  const float* bih  = (const float*)d_in[14];
  const float* bhh  = (const float*)d_in[15];
  // d_in[16], d_in[17]: w_omega/u_omega — result discarded by reference

  float* ws = (float*)d_ws;
  int*            off  = (int*)(ws + W_OFF);
  float*          deg2 = ws + W_DEG2;
  unsigned short* srt  = (unsigned short*)(ws + W_SRT);
  float*          ha   = ws + W_HA;
  float*          hb   = ws + W_HB;
  float*          gsum = ws + W_GSUM;
  float*          seq  = ws + W_SEQ;
  float*          pg4  = ws + W_PG;
  unsigned int*   w16  = (unsigned int*)(ws + W_W16);

  hipMemsetAsync(gsum, 0, 1024 * 4, stream);
  k_sort<<<256, 1024, SORT_LDS_BYTES, stream>>>(esrc, edst, off, (float2*)deg2, srt);
  k_w16<<<512, 256, 0, stream>>>(Whh, w16);
  k_conv<2, 12, true,  false><<<4096, 256, 0, stream>>>(off, srt, deg2, g1w, g1b, ha, nullptr);
  k_conv<12, 12, false, false><<<4096, 256, 0, stream>>>(off, srt, ha, g2w, g2b, hb, nullptr);
  k_conv<12, 4, false, true ><<<4096, 256, 0, stream>>>(off, srt, hb, g3w, g3b, nullptr, gsum);
  k_small<<<1, 256, 0, stream>>>(x, fc1w, fc1b, gsum, seq);
  k_pregates<<<1024, 256, 0, stream>>>(Wih, bih, bhh, seq, pg4);
  k_lstm<<<1, 1024, LSTM_LDS_BYTES, stream>>>(w16, pg4, (float*)d_out);
}

// Round 6
// 1009.845 us; speedup vs baseline: 1.4245x; 1.1931x over previous
//
#include <hip/hip_runtime.h>
#include <hip/hip_fp16.h>

#define NTOT (1u<<20)   // nodes total
#define ETOT (1u<<24)   // edges total
#define NG   256        // graphs
#define NPG  4096       // nodes per graph
#define EPG  65536      // edges per graph

// ---------------- workspace layout (in 4-byte words) ----------------
constexpr size_t W_OFF  = 0;                       // (NTOT+64) ints: CSR row offsets (global positions)
constexpr size_t W_DEG2 = W_OFF + NTOT + 64;       // NTOT float2: (indeg, outdeg)
constexpr size_t W_SRT  = W_DEG2 + 2*(size_t)NTOT; // ETOT ushorts = ETOT/2 words: sorted local src ids
constexpr size_t W_HA   = W_SRT + ETOT/2;          // NTOT*12 f32
constexpr size_t W_HB   = W_HA + (size_t)NTOT*12;  // NTOT*12 f32
constexpr size_t W_GSUM = W_HB + (size_t)NTOT*12;  // 256*4 f32
constexpr size_t W_SEQ  = W_GSUM + 1024;           // 256*32 f32
constexpr size_t W_PG   = W_SEQ + 8192;            // 256*256*4 f32 pregates (float4 per (step,row))
constexpr size_t W_W16  = W_PG + 262144;           // 131072 words: W_hh f16 pairs, permuted (see k_w16)
constexpr size_t W_SYNC = W_W16 + 131072;          // hbuf[2][128] uints + ctr (260 words)

// ---------------- per-graph counting sort (CSR by dst), scatter staged in LDS ----------------
// LDS: [0,16K) cur | [16K,20K) bscan | [20K,148K) region C = hd[16K]+hs[16K], reused as slds[128K]
#define SORT_LDS_BYTES (16384 + 4096 + 131072)
__global__ __launch_bounds__(1024) void k_sort(const int* __restrict__ esrc,
                                               const int* __restrict__ edst,
                                               int* __restrict__ off,
                                               float2* __restrict__ deg2,
                                               unsigned short* __restrict__ srt) {
  extern __shared__ char sm[];
  int* cur   = (int*)sm;                   // [4096]
  int* bscan = (int*)(sm + 16384);         // [1024]
  int* hd    = (int*)(sm + 20480);         // [4096]
  int* hs    = (int*)(sm + 20480 + 16384); // [4096]
  unsigned short* slds = (unsigned short*)(sm + 20480);  // [65536], reuses hd/hs space
  const int g = blockIdx.x;
  const int t = threadIdx.x;
  const int ebase = g * EPG;
  const int nbase = g * NPG;
  for (int i = t; i < NPG; i += 1024) { hd[i] = 0; hs[i] = 0; }
  __syncthreads();
  for (int e = t; e < EPG; e += 1024) {
    int s = esrc[ebase + e] - nbase;
    int d = edst[ebase + e] - nbase;
    atomicAdd(&hs[s], 1);
    atomicAdd(&hd[d], 1);
  }
  __syncthreads();
  // exclusive scan of hd[4096]: 4 per thread + Hillis-Steele over 1024 chunk sums
  int a0 = hd[t*4+0], a1 = hd[t*4+1], a2 = hd[t*4+2], a3 = hd[t*4+3];
  int csum = a0 + a1 + a2 + a3;
  bscan[t] = csum;
  __syncthreads();
  for (int o = 1; o < 1024; o <<= 1) {
    int v = (t >= o) ? bscan[t - o] : 0;
    __syncthreads();
    bscan[t] += v;
    __syncthreads();
  }
  int e0 = bscan[t] - csum;  // exclusive chunk offset
  cur[t*4+0] = e0;
  cur[t*4+1] = e0 + a0;
  cur[t*4+2] = e0 + a0 + a1;
  cur[t*4+3] = e0 + a0 + a1 + a2;
  __syncthreads();
  for (int i = t; i < NPG; i += 1024) {
    off[nbase + i] = ebase + cur[i];
    deg2[nbase + i] = make_float2((float)hd[i], (float)hs[i]);
  }
  if (g == NG - 1 && t == 0) off[NTOT] = (int)ETOT;
  __syncthreads();   // hd/hs fully consumed; region C becomes slds
  // scatter pass into LDS: place src into dst bucket
  for (int e = t; e < EPG; e += 1024) {
    int s = esrc[ebase + e] - nbase;
    int d = edst[ebase + e] - nbase;
    int p = atomicAdd(&cur[d], 1);
    slds[p] = (unsigned short)s;
  }
  __syncthreads();
  // coalesced stream-out: 128KB as 8192 x uint4
  uint4* dstv = (uint4*)(srt + (size_t)ebase);
  const uint4* srcv = (const uint4*)slds;
  for (int i = t; i < 8192; i += 1024)
    dstv[i] = srcv[i];
}

// ---------------- graph conv: aggregate in-edges, then linear+relu ----------------
template<int FIN, int FOUT, bool DEGIN, bool POOL>
__global__ __launch_bounds__(256) void k_conv(const int* __restrict__ off,
                                              const unsigned short* __restrict__ srt,
                                              const float* __restrict__ hin,
                                              const float* __restrict__ W,
                                              const float* __restrict__ Bv,
                                              float* __restrict__ hout,
                                              float* __restrict__ gsum) {
  __shared__ float wsm[FOUT*FIN + FOUT];
  __shared__ float4 red[POOL ? 256 : 1];
  const int b = blockIdx.x;
  const int t = threadIdx.x;
  const int xcd = b & 7, slot = b >> 3;
  const int part = slot & 15, gidx = slot >> 4;   // 16 parts/graph, 32 graphs/XCD
  const int g = xcd + 8 * gidx;
  for (int i = t; i < FOUT*FIN + FOUT; i += 256)
    wsm[i] = (i < FOUT*FIN) ? W[i] : Bv[i - FOUT*FIN];
  __syncthreads();
  const int nbase = g * NPG;
  const int n = nbase + part * 256 + t;
  const int e0 = off[n], e1 = off[n + 1];
  float acc[FIN];
  #pragma unroll
  for (int j = 0; j < FIN; j++) acc[j] = 0.f;
  #pragma unroll 4
  for (int e = e0; e < e1; e++) {
    const int s = nbase + (int)srt[e];
    if constexpr (DEGIN) {
      float2 v = ((const float2*)hin)[s];
      acc[0] += v.x; acc[1] += v.y;
    } else {
      const float4* r = (const float4*)(hin + (size_t)s * 12);
      float4 v0 = r[0], v1 = r[1], v2 = r[2];
      acc[0] += v0.x; acc[1] += v0.y; acc[2]  += v0.z; acc[3]  += v0.w;
      acc[4] += v1.x; acc[5] += v1.y; acc[6]  += v1.z; acc[7]  += v1.w;
      acc[8] += v2.x; acc[9] += v2.y; acc[10] += v2.z; acc[11] += v2.w;
    }
  }
  float o[FOUT];
  #pragma unroll
  for (int j = 0; j < FOUT; j++) {
    float v = wsm[FOUT*FIN + j];
    #pragma unroll
    for (int kk = 0; kk < FIN; kk++) v += wsm[j*FIN + kk] * acc[kk];
    o[j] = fmaxf(v, 0.f);
  }
  if constexpr (!POOL) {
    float4* wout = (float4*)(hout + (size_t)n * 12);
    wout[0] = make_float4(o[0], o[1], o[2],  o[3]);
    wout[1] = make_float4(o[4], o[5], o[6],  o[7]);
    wout[2] = make_float4(o[8], o[9], o[10], o[11]);
  } else {
    red[t] = make_float4(o[0], o[1], o[2], o[3]);
    __syncthreads();
    for (int o2 = 128; o2 > 0; o2 >>= 1) {
      if (t < o2) {
        red[t].x += red[t + o2].x; red[t].y += red[t + o2].y;
        red[t].z += red[t + o2].z; red[t].w += red[t + o2].w;
      }
      __syncthreads();
    }
    if (t == 0) {
      atomicAdd(&gsum[g*4+0], red[0].x);
      atomicAdd(&gsum[g*4+1], red[0].y);
      atomicAdd(&gsum[g*4+2], red[0].z);
      atomicAdd(&gsum[g*4+3], red[0].w);
    }
  }
}

// ---------------- fc1 + concat -> seq [256][32] ----------------
__global__ __launch_bounds__(256) void k_small(const float* __restrict__ x,
                                               const float* __restrict__ fw,
                                               const float* __restrict__ fb,
                                               const float* __restrict__ gsum,
                                               float* __restrict__ seq) {
  const int t = threadIdx.x;  // graph / seq row
  float xv[64];
  #pragma unroll
  for (int k = 0; k < 64; k++) xv[k] = x[t*64 + k];
  for (int j = 0; j < 28; j++) {
    float acc = fb[j];
    #pragma unroll
    for (int k = 0; k < 64; k++) acc += fw[j*64 + k] * xv[k];
    seq[t*32 + j] = fmaxf(acc, 0.f);
  }
  #pragma unroll
  for (int f = 0; f < 4; f++)
    seq[t*32 + 28 + f] = gsum[t*4 + f] * (1.0f / 4096.0f);
}

// ---------------- input-side gates, transposed: pg4[(step*256+rt)*4 + gate] ----------------
__global__ __launch_bounds__(256) void k_pregates(const float* __restrict__ Wih,
                                                  const float* __restrict__ bih,
                                                  const float* __restrict__ bhh,
                                                  const float* __restrict__ seq,
                                                  float* __restrict__ pg4) {
  const int b = blockIdx.x;
  const int step = b >> 2;
  const int gate = b & 3;
  const int rt = threadIdx.x;
  const int row = gate * 256 + rt;
  const float* sr = seq + step * 32;
  float acc = bih[row] + bhh[row];
  const float4* wr = (const float4*)(Wih + (size_t)row * 32);
  #pragma unroll
  for (int c = 0; c < 8; c++) {
    float4 w = wr[c];
    acc += w.x * sr[4*c+0] + w.y * sr[4*c+1] + w.z * sr[4*c+2] + w.w * sr[4*c+3];
  }
  pg4[((size_t)step * 256 + rt) * 4 + gate] = acc;
}

// ---------------- W_hh f32 -> f16 pairs, permuted for the 8-WG DPP-GEMV ----------------
// w16 flat uint index = wg*16384 + p*2048 + rd*1024 + t*4 + comp  (u = rd*4+comp):
//   = W_hh[row wg*32 + p*4 + r + 256*wv][f16 cols 2c,2c+1], c = g*8+u,
//   where wv=t>>6, r=(t>>4)&3, g=t&15.  (lane-consecutive uint4 -> conflict-floor b128)
__global__ __launch_bounds__(256) void k_w16(const float* __restrict__ Whh,
                                             unsigned int* __restrict__ w16) {
  const int pid = blockIdx.x * 256 + threadIdx.x;   // [0, 131072)
  const int wg = pid >> 14;
  const int rem = pid & 16383;
  const int p = rem >> 11;
  const int rd = (rem >> 10) & 1;
  const int t = (rem >> 2) & 255;
  const int comp = rem & 3;
  const int u = rd * 4 + comp;
  const int wv = t >> 6, r = (t >> 4) & 3, g = t & 15;
  const int R = wg * 32 + p * 4 + r + 256 * wv;
  const int c = g * 8 + u;
  float2 v = ((const float2*)Whh)[(size_t)R * 128 + c];
  __half2 h = __floats2half2_rn(v.x, v.y);
  w16[pid] = *(unsigned int*)&h;
}

// ---------------- LSTM: 8 cooperative WGs, weights fully LDS-resident ----------------
typedef _Float16 half2_t __attribute__((ext_vector_type(2)));

__device__ inline float dot2(unsigned int a, unsigned int b, float c) {
  return __builtin_amdgcn_fdot2(__builtin_bit_cast(half2_t, a),
                                __builtin_bit_cast(half2_t, b), c, false);
}

// sum across each 16-lane group via DPP row_shr (lane l%16==15 holds the sum)
__device__ inline float red16(float v) {
  int x;
  x = __builtin_amdgcn_update_dpp(0, __builtin_bit_cast(int, v), 0x111, 0xF, 0xF, false);
  v += __builtin_bit_cast(float, x);
  x = __builtin_amdgcn_update_dpp(0, __builtin_bit_cast(int, v), 0x112, 0xF, 0xF, false);
  v += __builtin_bit_cast(float, x);
  x = __builtin_amdgcn_update_dpp(0, __builtin_bit_cast(int, v), 0x114, 0xF, 0xF, false);
  v += __builtin_bit_cast(float, x);
  x = __builtin_amdgcn_update_dpp(0, __builtin_bit_cast(int, v), 0x118, 0xF, 0xF, false);
  v += __builtin_bit_cast(float, x);
  return v;
}

__device__ inline float fast_sig(float x) { return 1.f / (1.f + __expf(-x)); }
__device__ inline float fast_tanh(float x) {
  float xc = fminf(fmaxf(x, -30.f), 30.f);
  float e = __expf(2.f * xc);
  return (e - 1.f) / (e + 1.f);
}

// LDS: [0,64K) weights (4096 uint4) | [64K, 64K+512) gex[128] f32
#define L8_LDS_BYTES (65536 + 512)

// WG wg (of 8), 256 thr = 4 waves. Wave wv owns gate wv, rows wg*32+[0,32).
// Lane l=r*16+g holds h-slice pairs [g*8,g*8+8) in 8 VGPRs (4 b64 agent loads).
// 8 passes x {2 lane-consecutive ds_read_b128, 8 dot2, red16}. Cross-WG sync:
// monotonic arrival counter (release-add / acquire-poll), h double-buffered.
__global__ __launch_bounds__(256) void k_lstm8(const unsigned int* __restrict__ w16,
                                               const float* __restrict__ pg4,
                                               unsigned int* __restrict__ hbuf,
                                               unsigned int* __restrict__ ctr,
                                               float* __restrict__ out) {
  extern __shared__ char smem[];
  uint4* wl4 = (uint4*)smem;              // [4096]
  float* gex = (float*)(smem + 65536);    // [128]
  const int wg = blockIdx.x;
  const int t = threadIdx.x;
  const int l = t & 63, g = l & 15;
  // stage this WG's 64KB weight slice (linear copy, coalesced both sides)
  const uint4* g4 = (const uint4*)(w16 + (size_t)wg * 16384);
  #pragma unroll
  for (int k = 0; k < 16; k++) wl4[t + k * 256] = g4[t + k * 256];
  float cs = 0.f;                         // c_state, live in t<32
  __syncthreads();
  const int gexi0 = (t & 3) * 8 + (t >> 2);   // nonlin gex base (valid t<32)
  for (int step = 0; step < 256; ++step) {
    if (t == 0) {
      while (__hip_atomic_load(ctr, __ATOMIC_ACQUIRE, __HIP_MEMORY_SCOPE_AGENT)
             < (unsigned)(8 * step)) {}
    }
    __syncthreads();
    // own h slice: 4 x b64 agent loads (L2-bypassing, coherent with remote writers)
    const unsigned long long* hb =
        (const unsigned long long*)(hbuf + (step & 1) * 128);
    unsigned long long q0 = __hip_atomic_load(hb + g*4 + 0, __ATOMIC_RELAXED, __HIP_MEMORY_SCOPE_AGENT);
    unsigned long long q1 = __hip_atomic_load(hb + g*4 + 1, __ATOMIC_RELAXED, __HIP_MEMORY_SCOPE_AGENT);
    unsigned long long q2 = __hip_atomic_load(hb + g*4 + 2, __ATOMIC_RELAXED, __HIP_MEMORY_SCOPE_AGENT);
    unsigned long long q3 = __hip_atomic_load(hb + g*4 + 3, __ATOMIC_RELAXED, __HIP_MEMORY_SCOPE_AGENT);
    const unsigned int h0 = (unsigned int)q0, h1 = (unsigned int)(q0 >> 32);
    const unsigned int h2 = (unsigned int)q1, h3 = (unsigned int)(q1 >> 32);
    const unsigned int h4 = (unsigned int)q2, h5 = (unsigned int)(q2 >> 32);
    const unsigned int h6 = (unsigned int)q3, h7 = (unsigned int)(q3 >> 32);
    // prefetch pregates for the nonlin phase (independent of gex)
    float4 pf;
    if (t < 32)
      pf = *(const float4*)(pg4 + ((size_t)step * 256 + wg * 32 + t) * 4);
    float res[4];
    #pragma unroll
    for (int p = 0; p < 8; ++p) {
      const uint4 w0 = wl4[p * 512 + t];
      const uint4 w1 = wl4[p * 512 + 256 + t];
      float s = 0.f;
      s = dot2(w0.x, h0, s);
      s = dot2(w0.y, h1, s);
      s = dot2(w0.z, h2, s);
      s = dot2(w0.w, h3, s);
      s = dot2(w1.x, h4, s);
      s = dot2(w1.y, h5, s);
      s = dot2(w1.z, h6, s);
      s = dot2(w1.w, h7, s);
      res[p & 3] = red16(s);
      if ((p & 3) == 3 && (l & 15) == 15)
        *(float4*)(gex + (t >> 6) * 32 + ((l >> 4) & 3) * 8 + (p - 3)) =
            make_float4(res[0], res[1], res[2], res[3]);
    }
    __syncthreads();
    if (t < 32) {
      float gi = gex[ 0 + gexi0] + pf.x;
      float gf = gex[32 + gexi0] + pf.y;
      float gg = gex[64 + gexi0] + pf.z;
      float go = gex[96 + gexi0] + pf.w;
      float si = fast_sig(gi);
      float sf = fast_sig(gf);
      float so = fast_sig(go);
      float tg = fast_tanh(gg);
      cs = sf * cs + si * tg;
      float hn = so * fast_tanh(cs);
      out[step * 256 + wg * 32 + t] = hn;
      float he = __shfl(hn, (t & 15) * 2);
      float ho = __shfl(hn, (t & 15) * 2 + 1);
      if (t < 16) {
        __half2 hp = __floats2half2_rn(he, ho);
        __hip_atomic_store(hbuf + ((step + 1) & 1) * 128 + wg * 16 + t,
                           *(unsigned int*)&hp,
                           __ATOMIC_RELAXED, __HIP_MEMORY_SCOPE_AGENT);
      }
    }
    __syncthreads();   // drains wave0's h stores (vmcnt 0) + protects gex reuse
    if (t == 0)
      __hip_atomic_fetch_add(ctr, 1u, __ATOMIC_RELEASE, __HIP_MEMORY_SCOPE_AGENT);
  }
}

extern "C" void kernel_launch(void* const* d_in, const int* in_sizes, int n_in,
                              void* d_out, int out_size, void* d_ws, size_t ws_size,
                              hipStream_t stream) {
  const float* x    = (const float*)d_in[0];
  const int*   esrc = (const int*)d_in[1];
  const int*   edst = (const int*)d_in[2];
  // d_in[3] node_graph_ids: implied by node index (n >> 12)
  const float* fc1w = (const float*)d_in[4];
  const float* fc1b = (const float*)d_in[5];
  const float* g1w  = (const float*)d_in[6];
  const float* g1b  = (const float*)d_in[7];
  const float* g2w  = (const float*)d_in[8];
  const float* g2b  = (const float*)d_in[9];
  const float* g3w  = (const float*)d_in[10];
  const float* g3b  = (const float*)d_in[11];
  const float* Wih  = (const float*)d_in[12];
  const float* Whh  = (const float*)d_in[13];
  const float* bih  = (const float*)d_in[14];
  const float* bhh  = (const float*)d_in[15];
  // d_in[16], d_in[17]: w_omega/u_omega — result discarded by reference

  float* ws = (float*)d_ws;
  int*            off  = (int*)(ws + W_OFF);
  float*          deg2 = ws + W_DEG2;
  unsigned short* srt  = (unsigned short*)(ws + W_SRT);
  float*          ha   = ws + W_HA;
  float*          hb   = ws + W_HB;
  float*          gsum = ws + W_GSUM;
  float*          seq  = ws + W_SEQ;
  float*          pg4  = ws + W_PG;
  unsigned int*   w16  = (unsigned int*)(ws + W_W16);
  unsigned int*   hbuf = (unsigned int*)(ws + W_SYNC);        // [2][128]
  unsigned int*   ctr  = (unsigned int*)(ws + W_SYNC) + 256;  // arrival counter

  hipMemsetAsync(gsum, 0, 1024 * 4, stream);
  hipMemsetAsync(hbuf, 0, (256 + 4) * 4, stream);   // h double-buffer + ctr = 0
  k_sort<<<256, 1024, SORT_LDS_BYTES, stream>>>(esrc, edst, off, (float2*)deg2, srt);
  k_w16<<<512, 256, 0, stream>>>(Whh, w16);
  k_conv<2, 12, true,  false><<<4096, 256, 0, stream>>>(off, srt, deg2, g1w, g1b, ha, nullptr);
  k_conv<12, 12, false, false><<<4096, 256, 0, stream>>>(off, srt, ha, g2w, g2b, hb, nullptr);
  k_conv<12, 4, false, true ><<<4096, 256, 0, stream>>>(off, srt, hb, g3w, g3b, nullptr, gsum);
  k_small<<<1, 256, 0, stream>>>(x, fc1w, fc1b, gsum, seq);
  k_pregates<<<1024, 256, 0, stream>>>(Wih, bih, bhh, seq, pg4);
  k_lstm8<<<8, 256, L8_LDS_BYTES, stream>>>(w16, pg4, hbuf, ctr, (float*)d_out);
}

// Round 7
// 921.954 us; speedup vs baseline: 1.5603x; 1.0953x over previous
//
#include <hip/hip_runtime.h>
#include <hip/hip_fp16.h>

#define NTOT (1u<<20)   // nodes total
#define ETOT (1u<<24)   // edges total
#define NG   256        // graphs
#define NPG  4096       // nodes per graph
#define EPG  65536      // edges per graph

// ---------------- workspace layout (in 4-byte words) ----------------
constexpr size_t W_OFF  = 0;                       // (NTOT+64) ints: CSR row offsets (global positions)
constexpr size_t W_DEG2 = W_OFF + NTOT + 64;       // NTOT float2: (indeg, outdeg)
constexpr size_t W_SRT  = W_DEG2 + 2*(size_t)NTOT; // ETOT ushorts = ETOT/2 words: sorted local src ids
constexpr size_t W_HA   = W_SRT + ETOT/2;          // NTOT*12 f32
constexpr size_t W_HB   = W_HA + (size_t)NTOT*12;  // NTOT*12 f32
constexpr size_t W_GSUM = W_HB + (size_t)NTOT*12;  // 256*4 f32
constexpr size_t W_SEQ  = W_GSUM + 1024;           // 256*32 f32
constexpr size_t W_PG   = W_SEQ + 8192;            // 256*256*4 f32 pregates (float4 per (step,row))
constexpr size_t W_W16  = W_PG + 262144;           // 131072 words: W_hh f16 pairs, permuted (see k_w16)
constexpr size_t W_SYNC = W_W16 + 131072;          // tagged h: u64[2][128] = 512 words

// ---------------- per-graph counting sort (CSR by dst), scatter staged in LDS ----------------
// LDS: [0,16K) cur | [16K,20K) bscan | [20K,148K) region C = hd[16K]+hs[16K], reused as slds[128K]
#define SORT_LDS_BYTES (16384 + 4096 + 131072)
__global__ __launch_bounds__(1024) void k_sort(const int* __restrict__ esrc,
                                               const int* __restrict__ edst,
                                               int* __restrict__ off,
                                               float2* __restrict__ deg2,
                                               unsigned short* __restrict__ srt) {
  extern __shared__ char sm[];
  int* cur   = (int*)sm;                   // [4096]
  int* bscan = (int*)(sm + 16384);         // [1024]
  int* hd    = (int*)(sm + 20480);         // [4096]
  int* hs    = (int*)(sm + 20480 + 16384); // [4096]
  unsigned short* slds = (unsigned short*)(sm + 20480);  // [65536], reuses hd/hs space
  const int g = blockIdx.x;
  const int t = threadIdx.x;
  const int ebase = g * EPG;
  const int nbase = g * NPG;
  for (int i = t; i < NPG; i += 1024) { hd[i] = 0; hs[i] = 0; }
  __syncthreads();
  for (int e = t; e < EPG; e += 1024) {
    int s = esrc[ebase + e] - nbase;
    int d = edst[ebase + e] - nbase;
    atomicAdd(&hs[s], 1);
    atomicAdd(&hd[d], 1);
  }
  __syncthreads();
  // exclusive scan of hd[4096]: 4 per thread + Hillis-Steele over 1024 chunk sums
  int a0 = hd[t*4+0], a1 = hd[t*4+1], a2 = hd[t*4+2], a3 = hd[t*4+3];
  int csum = a0 + a1 + a2 + a3;
  bscan[t] = csum;
  __syncthreads();
  for (int o = 1; o < 1024; o <<= 1) {
    int v = (t >= o) ? bscan[t - o] : 0;
    __syncthreads();
    bscan[t] += v;
    __syncthreads();
  }
  int e0 = bscan[t] - csum;  // exclusive chunk offset
  cur[t*4+0] = e0;
  cur[t*4+1] = e0 + a0;
  cur[t*4+2] = e0 + a0 + a1;
  cur[t*4+3] = e0 + a0 + a1 + a2;
  __syncthreads();
  for (int i = t; i < NPG; i += 1024) {
    off[nbase + i] = ebase + cur[i];
    deg2[nbase + i] = make_float2((float)hd[i], (float)hs[i]);
  }
  if (g == NG - 1 && t == 0) off[NTOT] = (int)ETOT;
  __syncthreads();   // hd/hs fully consumed; region C becomes slds
  // scatter pass into LDS: place src into dst bucket
  for (int e = t; e < EPG; e += 1024) {
    int s = esrc[ebase + e] - nbase;
    int d = edst[ebase + e] - nbase;
    int p = atomicAdd(&cur[d], 1);
    slds[p] = (unsigned short)s;
  }
  __syncthreads();
  // coalesced stream-out: 128KB as 8192 x uint4
  uint4* dstv = (uint4*)(srt + (size_t)ebase);
  const uint4* srcv = (const uint4*)slds;
  for (int i = t; i < 8192; i += 1024)
    dstv[i] = srcv[i];
}

// ---------------- graph conv: aggregate in-edges, then linear+relu ----------------
template<int FIN, int FOUT, bool DEGIN, bool POOL>
__global__ __launch_bounds__(256) void k_conv(const int* __restrict__ off,
                                              const unsigned short* __restrict__ srt,
                                              const float* __restrict__ hin,
                                              const float* __restrict__ W,
                                              const float* __restrict__ Bv,
                                              float* __restrict__ hout,
                                              float* __restrict__ gsum) {
  __shared__ float wsm[FOUT*FIN + FOUT];
  __shared__ float4 red[POOL ? 256 : 1];
  const int b = blockIdx.x;
  const int t = threadIdx.x;
  const int xcd = b & 7, slot = b >> 3;
  const int part = slot & 15, gidx = slot >> 4;   // 16 parts/graph, 32 graphs/XCD
  const int g = xcd + 8 * gidx;
  for (int i = t; i < FOUT*FIN + FOUT; i += 256)
    wsm[i] = (i < FOUT*FIN) ? W[i] : Bv[i - FOUT*FIN];
  __syncthreads();
  const int nbase = g * NPG;
  const int n = nbase + part * 256 + t;
  const int e0 = off[n], e1 = off[n + 1];
  float acc[FIN];
  #pragma unroll
  for (int j = 0; j < FIN; j++) acc[j] = 0.f;
  #pragma unroll 4
  for (int e = e0; e < e1; e++) {
    const int s = nbase + (int)srt[e];
    if constexpr (DEGIN) {
      float2 v = ((const float2*)hin)[s];
      acc[0] += v.x; acc[1] += v.y;
    } else {
      const float4* r = (const float4*)(hin + (size_t)s * 12);
      float4 v0 = r[0], v1 = r[1], v2 = r[2];
      acc[0] += v0.x; acc[1] += v0.y; acc[2]  += v0.z; acc[3]  += v0.w;
      acc[4] += v1.x; acc[5] += v1.y; acc[6]  += v1.z; acc[7]  += v1.w;
      acc[8] += v2.x; acc[9] += v2.y; acc[10] += v2.z; acc[11] += v2.w;
    }
  }
  float o[FOUT];
  #pragma unroll
  for (int j = 0; j < FOUT; j++) {
    float v = wsm[FOUT*FIN + j];
    #pragma unroll
    for (int kk = 0; kk < FIN; kk++) v += wsm[j*FIN + kk] * acc[kk];
    o[j] = fmaxf(v, 0.f);
  }
  if constexpr (!POOL) {
    float4* wout = (float4*)(hout + (size_t)n * 12);
    wout[0] = make_float4(o[0], o[1], o[2],  o[3]);
    wout[1] = make_float4(o[4], o[5], o[6],  o[7]);
    wout[2] = make_float4(o[8], o[9], o[10], o[11]);
  } else {
    red[t] = make_float4(o[0], o[1], o[2], o[3]);
    __syncthreads();
    for (int o2 = 128; o2 > 0; o2 >>= 1) {
      if (t < o2) {
        red[t].x += red[t + o2].x; red[t].y += red[t + o2].y;
        red[t].z += red[t + o2].z; red[t].w += red[t + o2].w;
      }
      __syncthreads();
    }
    if (t == 0) {
      atomicAdd(&gsum[g*4+0], red[0].x);
      atomicAdd(&gsum[g*4+1], red[0].y);
      atomicAdd(&gsum[g*4+2], red[0].z);
      atomicAdd(&gsum[g*4+3], red[0].w);
    }
  }
}

// ---------------- fc1 + concat -> seq [256][32] ----------------
__global__ __launch_bounds__(256) void k_small(const float* __restrict__ x,
                                               const float* __restrict__ fw,
                                               const float* __restrict__ fb,
                                               const float* __restrict__ gsum,
                                               float* __restrict__ seq) {
  const int t = threadIdx.x;  // graph / seq row
  float xv[64];
  #pragma unroll
  for (int k = 0; k < 64; k++) xv[k] = x[t*64 + k];
  for (int j = 0; j < 28; j++) {
    float acc = fb[j];
    #pragma unroll
    for (int k = 0; k < 64; k++) acc += fw[j*64 + k] * xv[k];
    seq[t*32 + j] = fmaxf(acc, 0.f);
  }
  #pragma unroll
  for (int f = 0; f < 4; f++)
    seq[t*32 + 28 + f] = gsum[t*4 + f] * (1.0f / 4096.0f);
}

// ---------------- input-side gates, transposed: pg4[(step*256+rt)*4 + gate] ----------------
__global__ __launch_bounds__(256) void k_pregates(const float* __restrict__ Wih,
                                                  const float* __restrict__ bih,
                                                  const float* __restrict__ bhh,
                                                  const float* __restrict__ seq,
                                                  float* __restrict__ pg4) {
  const int b = blockIdx.x;
  const int step = b >> 2;
  const int gate = b & 3;
  const int rt = threadIdx.x;
  const int row = gate * 256 + rt;
  const float* sr = seq + step * 32;
  float acc = bih[row] + bhh[row];
  const float4* wr = (const float4*)(Wih + (size_t)row * 32);
  #pragma unroll
  for (int c = 0; c < 8; c++) {
    float4 w = wr[c];
    acc += w.x * sr[4*c+0] + w.y * sr[4*c+1] + w.z * sr[4*c+2] + w.w * sr[4*c+3];
  }
  pg4[((size_t)step * 256 + rt) * 4 + gate] = acc;
}

// ---------------- W_hh f32 -> f16 pairs, permuted for the 8-WG DPP-GEMV ----------------
// w16 flat uint index = wg*16384 + p*2048 + rd*1024 + t*4 + comp  (u = rd*4+comp):
//   = W_hh[row wg*32 + p*4 + r + 256*wv][f16 cols 2c,2c+1], c = g*8+u,
//   where wv=t>>6, r=(t>>4)&3, g=t&15.  (lane-consecutive uint4 -> conflict-floor b128)
__global__ __launch_bounds__(256) void k_w16(const float* __restrict__ Whh,
                                             unsigned int* __restrict__ w16) {
  const int pid = blockIdx.x * 256 + threadIdx.x;   // [0, 131072)
  const int wg = pid >> 14;
  const int rem = pid & 16383;
  const int p = rem >> 11;
  const int rd = (rem >> 10) & 1;
  const int t = (rem >> 2) & 255;
  const int comp = rem & 3;
  const int u = rd * 4 + comp;
  const int wv = t >> 6, r = (t >> 4) & 3, g = t & 15;
  const int R = wg * 32 + p * 4 + r + 256 * wv;
  const int c = g * 8 + u;
  float2 v = ((const float2*)Whh)[(size_t)R * 128 + c];
  __half2 h = __floats2half2_rn(v.x, v.y);
  w16[pid] = *(unsigned int*)&h;
}

// ---------------- LSTM: 8 cooperative WGs, tagged-h single-RTT sync ----------------
typedef _Float16 half2_t __attribute__((ext_vector_type(2)));

__device__ inline float dot2(unsigned int a, unsigned int b, float c) {
  return __builtin_amdgcn_fdot2(__builtin_bit_cast(half2_t, a),
                                __builtin_bit_cast(half2_t, b), c, false);
}

// sum across each 16-lane group via DPP row_shr (lane l%16==15 holds the sum)
__device__ inline float red16(float v) {
  int x;
  x = __builtin_amdgcn_update_dpp(0, __builtin_bit_cast(int, v), 0x111, 0xF, 0xF, false);
  v += __builtin_bit_cast(float, x);
  x = __builtin_amdgcn_update_dpp(0, __builtin_bit_cast(int, v), 0x112, 0xF, 0xF, false);
  v += __builtin_bit_cast(float, x);
  x = __builtin_amdgcn_update_dpp(0, __builtin_bit_cast(int, v), 0x114, 0xF, 0xF, false);
  v += __builtin_bit_cast(float, x);
  x = __builtin_amdgcn_update_dpp(0, __builtin_bit_cast(int, v), 0x118, 0xF, 0xF, false);
  v += __builtin_bit_cast(float, x);
  return v;
}

__device__ inline float fast_sig(float x) { return 1.f / (1.f + __expf(-x)); }
__device__ inline float fast_tanh(float x) {
  float xc = fminf(fmaxf(x, -30.f), 30.f);
  float e = __expf(2.f * xc);
  return (e - 1.f) / (e + 1.f);
}

// LDS: [0,64K) weights (4096 uint4) | [64K, 64K+512) gex[128] f32
#define L8_LDS_BYTES (65536 + 512)

// WG wg (of 8), 256 thr = 4 waves. Wave wv owns gate wv, rows wg*32+[0,32).
// Lane l=r*16+g holds h-slice pairs [g*8,g*8+8). h exchange: tagged u64 words
// hbuf[slot=step&1][uint k] = (tag<<32)|data, tag = step this h is INPUT for.
// Consumers poll directly on their 8 words: detection==data, 1 RTT. memset(0)
// encodes the initial state (tag0, h0=0). 2 slots + tag equality is skew-safe:
// writing tag s+2 into slot p requires all tag-s+1 reads done, which requires
// every WG finished step s (and thus consumed slot p's tag-s values).
__global__ __launch_bounds__(256) void k_lstm8(const unsigned int* __restrict__ w16,
                                               const float* __restrict__ pg4,
                                               unsigned long long* __restrict__ hbuf,
                                               float* __restrict__ out) {
  extern __shared__ char smem[];
  uint4* wl4 = (uint4*)smem;              // [4096]
  float* gex = (float*)(smem + 65536);    // [128]
  const int wg = blockIdx.x;
  const int t = threadIdx.x;
  const int l = t & 63, g = l & 15;
  // stage this WG's 64KB weight slice (linear copy, coalesced both sides)
  const uint4* g4 = (const uint4*)(w16 + (size_t)wg * 16384);
  #pragma unroll
  for (int k = 0; k < 16; k++) wl4[t + k * 256] = g4[t + k * 256];
  float cs = 0.f;                         // c_state, live in t<32
  __syncthreads();
  const int gexi0 = (t & 3) * 8 + (t >> 2);   // nonlin gex base (valid t<32)
  for (int step = 0; step < 256; ++step) {
    // prefetch pregates (independent of h) before the poll
    float4 pf;
    if (t < 32)
      pf = *(const float4*)(pg4 + ((size_t)step * 256 + wg * 32 + t) * 4);
    // poll own 8 tagged words: tag == step means data ready
    const unsigned long long* hb = hbuf + (step & 1) * 128 + 8 * g;
    unsigned long long v0, v1, v2, v3, v4, v5, v6, v7;
    for (;;) {
      v0 = __hip_atomic_load(hb + 0, __ATOMIC_RELAXED, __HIP_MEMORY_SCOPE_AGENT);
      v1 = __hip_atomic_load(hb + 1, __ATOMIC_RELAXED, __HIP_MEMORY_SCOPE_AGENT);
      v2 = __hip_atomic_load(hb + 2, __ATOMIC_RELAXED, __HIP_MEMORY_SCOPE_AGENT);
      v3 = __hip_atomic_load(hb + 3, __ATOMIC_RELAXED, __HIP_MEMORY_SCOPE_AGENT);
      v4 = __hip_atomic_load(hb + 4, __ATOMIC_RELAXED, __HIP_MEMORY_SCOPE_AGENT);
      v5 = __hip_atomic_load(hb + 5, __ATOMIC_RELAXED, __HIP_MEMORY_SCOPE_AGENT);
      v6 = __hip_atomic_load(hb + 6, __ATOMIC_RELAXED, __HIP_MEMORY_SCOPE_AGENT);
      v7 = __hip_atomic_load(hb + 7, __ATOMIC_RELAXED, __HIP_MEMORY_SCOPE_AGENT);
      unsigned tagmin = (unsigned)(v0 >> 32);
      tagmin = min(tagmin, (unsigned)(v1 >> 32));
      tagmin = min(tagmin, (unsigned)(v2 >> 32));
      tagmin = min(tagmin, (unsigned)(v3 >> 32));
      tagmin = min(tagmin, (unsigned)(v4 >> 32));
      tagmin = min(tagmin, (unsigned)(v5 >> 32));
      tagmin = min(tagmin, (unsigned)(v6 >> 32));
      tagmin = min(tagmin, (unsigned)(v7 >> 32));
      if (tagmin == (unsigned)step) break;
    }
    const unsigned int h0 = (unsigned int)v0, h1 = (unsigned int)v1;
    const unsigned int h2 = (unsigned int)v2, h3 = (unsigned int)v3;
    const unsigned int h4 = (unsigned int)v4, h5 = (unsigned int)v5;
    const unsigned int h6 = (unsigned int)v6, h7 = (unsigned int)v7;
    float res[4];
    #pragma unroll
    for (int p = 0; p < 8; ++p) {
      const uint4 w0 = wl4[p * 512 + t];
      const uint4 w1 = wl4[p * 512 + 256 + t];
      float s = 0.f;
      s = dot2(w0.x, h0, s);
      s = dot2(w0.y, h1, s);
      s = dot2(w0.z, h2, s);
      s = dot2(w0.w, h3, s);
      s = dot2(w1.x, h4, s);
      s = dot2(w1.y, h5, s);
      s = dot2(w1.z, h6, s);
      s = dot2(w1.w, h7, s);
      res[p & 3] = red16(s);
      if ((p & 3) == 3 && (l & 15) == 15)
        *(float4*)(gex + (t >> 6) * 32 + ((l >> 4) & 3) * 8 + (p - 3)) =
            make_float4(res[0], res[1], res[2], res[3]);
    }
    __syncthreads();   // gex writes (all waves) -> gex reads (wave 0)
    if (t < 32) {
      float gi = gex[ 0 + gexi0] + pf.x;
      float gf = gex[32 + gexi0] + pf.y;
      float gg = gex[64 + gexi0] + pf.z;
      float go = gex[96 + gexi0] + pf.w;
      float si = fast_sig(gi);
      float sf = fast_sig(gf);
      float so = fast_sig(go);
      float tg = fast_tanh(gg);
      cs = sf * cs + si * tg;
      float hn = so * fast_tanh(cs);
      out[step * 256 + wg * 32 + t] = hn;
      float he = __shfl(hn, (t & 15) * 2);
      float ho = __shfl(hn, (t & 15) * 2 + 1);
      if (t < 16) {
        __half2 hp = __floats2half2_rn(he, ho);
        unsigned long long w =
            ((unsigned long long)(step + 1) << 32) | *(unsigned int*)&hp;
        __hip_atomic_store(hbuf + ((step + 1) & 1) * 128 + wg * 16 + t, w,
                           __ATOMIC_RELAXED, __HIP_MEMORY_SCOPE_AGENT);
      }
    }
    // no trailing barrier: cross-step hazards are gated by the tag poll
  }
}

extern "C" void kernel_launch(void* const* d_in, const int* in_sizes, int n_in,
                              void* d_out, int out_size, void* d_ws, size_t ws_size,
                              hipStream_t stream) {
  const float* x    = (const float*)d_in[0];
  const int*   esrc = (const int*)d_in[1];
  const int*   edst = (const int*)d_in[2];
  // d_in[3] node_graph_ids: implied by node index (n >> 12)
  const float* fc1w = (const float*)d_in[4];
  const float* fc1b = (const float*)d_in[5];
  const float* g1w  = (const float*)d_in[6];
  const float* g1b  = (const float*)d_in[7];
  const float* g2w  = (const float*)d_in[8];
  const float* g2b  = (const float*)d_in[9];
  const float* g3w  = (const float*)d_in[10];
  const float* g3b  = (const float*)d_in[11];
  const float* Wih  = (const float*)d_in[12];
  const float* Whh  = (const float*)d_in[13];
  const float* bih  = (const float*)d_in[14];
  const float* bhh  = (const float*)d_in[15];
  // d_in[16], d_in[17]: w_omega/u_omega — result discarded by reference

  float* ws = (float*)d_ws;
  int*            off  = (int*)(ws + W_OFF);
  float*          deg2 = ws + W_DEG2;
  unsigned short* srt  = (unsigned short*)(ws + W_SRT);
  float*          ha   = ws + W_HA;
  float*          hb   = ws + W_HB;
  float*          gsum = ws + W_GSUM;
  float*          seq  = ws + W_SEQ;
  float*          pg4  = ws + W_PG;
  unsigned int*   w16  = (unsigned int*)(ws + W_W16);
  unsigned long long* hbuf = (unsigned long long*)(ws + W_SYNC);  // [2][128] tagged

  hipMemsetAsync(gsum, 0, 1024 * 4, stream);
  hipMemsetAsync(hbuf, 0, 2 * 128 * 8, stream);   // (tag0, h0=0) both slots
  k_sort<<<256, 1024, SORT_LDS_BYTES, stream>>>(esrc, edst, off, (float2*)deg2, srt);
  k_w16<<<512, 256, 0, stream>>>(Whh, w16);
  k_conv<2, 12, true,  false><<<4096, 256, 0, stream>>>(off, srt, deg2, g1w, g1b, ha, nullptr);
  k_conv<12, 12, false, false><<<4096, 256, 0, stream>>>(off, srt, ha, g2w, g2b, hb, nullptr);
  k_conv<12, 4, false, true ><<<4096, 256, 0, stream>>>(off, srt, hb, g3w, g3b, nullptr, gsum);
  k_small<<<1, 256, 0, stream>>>(x, fc1w, fc1b, gsum, seq);
  k_pregates<<<1024, 256, 0, stream>>>(Wih, bih, bhh, seq, pg4);
  k_lstm8<<<8, 256, L8_LDS_BYTES, stream>>>(w16, pg4, hbuf, (float*)d_out);
}

// Round 9
// 824.826 us; speedup vs baseline: 1.7440x; 1.1178x over previous
//
#include <hip/hip_runtime.h>
#include <hip/hip_fp16.h>

#define NTOT (1u<<20)   // nodes total
#define ETOT (1u<<24)   // edges total
#define NG   256        // graphs
#define NPG  4096       // nodes per graph
#define EPG  65536      // edges per graph

// ---------------- workspace layout (in 4-byte words) ----------------
constexpr size_t W_OFF  = 0;                       // (NTOT+64) ints: CSR row offsets (global positions)
constexpr size_t W_DEG2 = W_OFF + NTOT + 64;       // NTOT float2: (indeg, outdeg)
constexpr size_t W_SRT  = W_DEG2 + 2*(size_t)NTOT; // ETOT ushorts = ETOT/2 words: sorted local src ids
constexpr size_t W_HA   = W_SRT + ETOT/2;          // NTOT*12 f32
constexpr size_t W_HB   = W_HA + (size_t)NTOT*12;  // NTOT*12 f32
constexpr size_t W_GSUM = W_HB + (size_t)NTOT*12;  // 256*4 f32
constexpr size_t W_SEQ  = W_GSUM + 1024;           // 256*32 f32
constexpr size_t W_PG   = W_SEQ + 8192;            // 256*256*4 f32 pregates (float4 per (step,row))
constexpr size_t W_W16  = W_PG + 262144;           // 131072 words: W_hh f16 pairs, permuted (see k_w16)
constexpr size_t W_SYNC = W_W16 + 131072;          // tagged h: u64[2][128] = 512 words

// ---------------- per-graph counting sort (CSR by dst) + FUSED conv1 ----------------
// LDS: [0,16K) cur (cursors; reused as packed-deg u16x2 after scatter)
//      [16K,20K) bscan (scan; reused as conv1 weights after scatter)
//      [20K,148K) hd[16K]+hs[16K] hist, reused as slds[128K] sorted edge lists
#define SORT_LDS_BYTES (16384 + 4096 + 131072)
__global__ __launch_bounds__(1024) void k_sort(const int* __restrict__ esrc,
                                               const int* __restrict__ edst,
                                               int* __restrict__ off,
                                               float2* __restrict__ deg2,
                                               unsigned short* __restrict__ srt,
                                               const float* __restrict__ g1w,
                                               const float* __restrict__ g1b,
                                               float* __restrict__ ha) {
  extern __shared__ char sm[];
  int* cur   = (int*)sm;                   // [4096]
  int* bscan = (int*)(sm + 16384);         // [1024]
  int* hd    = (int*)(sm + 20480);         // [4096]
  int* hs    = (int*)(sm + 20480 + 16384); // [4096]
  unsigned short* slds = (unsigned short*)(sm + 20480);  // [65536], reuses hd/hs space
  const int g = blockIdx.x;
  const int t = threadIdx.x;
  const int ebase = g * EPG;
  const int nbase = g * NPG;
  for (int i = t; i < NPG; i += 1024) { hd[i] = 0; hs[i] = 0; }
  __syncthreads();
  for (int e = t; e < EPG; e += 1024) {
    int s = esrc[ebase + e] - nbase;
    int d = edst[ebase + e] - nbase;
    atomicAdd(&hs[s], 1);
    atomicAdd(&hd[d], 1);
  }
  __syncthreads();
  // exclusive scan of hd[4096]: 4 per thread + Hillis-Steele over 1024 chunk sums
  int a0 = hd[t*4+0], a1 = hd[t*4+1], a2 = hd[t*4+2], a3 = hd[t*4+3];
  int csum = a0 + a1 + a2 + a3;
  bscan[t] = csum;
  __syncthreads();
  for (int o = 1; o < 1024; o <<= 1) {
    int v = (t >= o) ? bscan[t - o] : 0;
    __syncthreads();
    bscan[t] += v;
    __syncthreads();
  }
  int e0 = bscan[t] - csum;  // exclusive chunk offset
  cur[t*4+0] = e0;
  cur[t*4+1] = e0 + a0;
  cur[t*4+2] = e0 + a0 + a1;
  cur[t*4+3] = e0 + a0 + a1 + a2;
  __syncthreads();
  for (int i = t; i < NPG; i += 1024) {
    off[nbase + i] = ebase + cur[i];
    deg2[nbase + i] = make_float2((float)hd[i], (float)hs[i]);
  }
  if (g == NG - 1 && t == 0) off[NTOT] = (int)ETOT;
  __syncthreads();   // hd/hs fully consumed; region C becomes slds
  // scatter pass into LDS: place src into dst bucket
  for (int e = t; e < EPG; e += 1024) {
    int s = esrc[ebase + e] - nbase;
    int d = edst[ebase + e] - nbase;
    int p = atomicAdd(&cur[d], 1);
    slds[p] = (unsigned short)s;
  }
  __syncthreads();   // cur/bscan dead from here; slds final
  // coalesced stream-out: 128KB as 8192 x uint4
  uint4* dstv = (uint4*)(srt + (size_t)ebase);
  const uint4* srcv = (const uint4*)slds;
  for (int i = t; i < 8192; i += 1024)
    dstv[i] = srcv[i];
  // ---- fused conv1 ----
  // stash weights (w[12][2] then b[12]) in dead bscan region
  if (t < 36) ((float*)bscan)[t] = (t < 24) ? g1w[t] : g1b[t - 24];
  // packed degrees (u16 indeg | u16 outdeg << 16) in dead cur region
  for (int i = t; i < NPG; i += 1024) {
    float2 d2 = deg2[nbase + i];              // own-block write, L2-hot
    cur[i] = (int)((unsigned)(int)d2.x | ((unsigned)(int)d2.y << 16));
  }
  __syncthreads();
  const float* wv = (const float*)bscan;
  for (int q = 0; q < 4; ++q) {
    const int nloc = q * 1024 + t;
    const int s0 = off[nbase + nloc] - ebase;  // own-block write, L2-hot
    const int s1 = (nloc == NPG - 1) ? EPG : (off[nbase + nloc + 1] - ebase);
    float acc0 = 0.f, acc1 = 0.f;
    for (int e = s0; e < s1; ++e) {
      unsigned pd = (unsigned)cur[(int)slds[e]];
      acc0 += (float)(pd & 0xFFFFu);
      acc1 += (float)(pd >> 16);
    }
    float o[12];
    #pragma unroll
    for (int j = 0; j < 12; j++)
      o[j] = fmaxf(wv[2*j] * acc0 + wv[2*j+1] * acc1 + wv[24 + j], 0.f);
    float4* wout = (float4*)(ha + (size_t)(nbase + nloc) * 12);
    wout[0] = make_float4(o[0], o[1], o[2],  o[3]);
    wout[1] = make_float4(o[4], o[5], o[6],  o[7]);
    wout[2] = make_float4(o[8], o[9], o[10], o[11]);
  }
}

// ---------------- graph conv (layers 2,3): aggregate in-edges, linear+relu ----------------
template<int FIN, int FOUT, bool POOL>
__global__ __launch_bounds__(256) void k_conv(const int* __restrict__ off,
                                              const unsigned short* __restrict__ srt,
                                              const float* __restrict__ hin,
                                              const float* __restrict__ W,
                                              const float* __restrict__ Bv,
                                              float* __restrict__ hout,
                                              float* __restrict__ gsum) {
  __shared__ float wsm[FOUT*FIN + FOUT];
  __shared__ float4 red[POOL ? 256 : 1];
  const int b = blockIdx.x;
  const int t = threadIdx.x;
  const int xcd = b & 7, slot = b >> 3;
  const int part = slot & 15, gidx = slot >> 4;   // 16 parts/graph, 32 graphs/XCD
  const int g = xcd + 8 * gidx;
  for (int i = t; i < FOUT*FIN + FOUT; i += 256)
    wsm[i] = (i < FOUT*FIN) ? W[i] : Bv[i - FOUT*FIN];
  __syncthreads();
  const int nbase = g * NPG;
  const int n = nbase + part * 256 + t;
  const int e0 = off[n], e1 = off[n + 1];
  float acc[FIN];
  #pragma unroll
  for (int j = 0; j < FIN; j++) acc[j] = 0.f;
  #pragma unroll 4
  for (int e = e0; e < e1; e++) {
    const int s = nbase + (int)srt[e];
    const float4* r = (const float4*)(hin + (size_t)s * 12);
    float4 v0 = r[0], v1 = r[1], v2 = r[2];
    acc[0] += v0.x; acc[1] += v0.y; acc[2]  += v0.z; acc[3]  += v0.w;
    acc[4] += v1.x; acc[5] += v1.y; acc[6]  += v1.z; acc[7]  += v1.w;
    acc[8] += v2.x; acc[9] += v2.y; acc[10] += v2.z; acc[11] += v2.w;
  }
  float o[FOUT];
  #pragma unroll
  for (int j = 0; j < FOUT; j++) {
    float v = wsm[FOUT*FIN + j];
    #pragma unroll
    for (int kk = 0; kk < FIN; kk++) v += wsm[j*FIN + kk] * acc[kk];
    o[j] = fmaxf(v, 0.f);
  }
  if constexpr (!POOL) {
    float4* wout = (float4*)(hout + (size_t)n * 12);
    wout[0] = make_float4(o[0], o[1], o[2],  o[3]);
    wout[1] = make_float4(o[4], o[5], o[6],  o[7]);
    wout[2] = make_float4(o[8], o[9], o[10], o[11]);
  } else {
    red[t] = make_float4(o[0], o[1], o[2], o[3]);
    __syncthreads();
    for (int o2 = 128; o2 > 0; o2 >>= 1) {
      if (t < o2) {
        red[t].x += red[t + o2].x; red[t].y += red[t + o2].y;
        red[t].z += red[t + o2].z; red[t].w += red[t + o2].w;
      }
      __syncthreads();
    }
    if (t == 0) {
      atomicAdd(&gsum[g*4+0], red[0].x);
      atomicAdd(&gsum[g*4+1], red[0].y);
      atomicAdd(&gsum[g*4+2], red[0].z);
      atomicAdd(&gsum[g*4+3], red[0].w);
    }
  }
}

// ---------------- fc1 + concat -> seq [256][32] ----------------
__global__ __launch_bounds__(256) void k_small(const float* __restrict__ x,
                                               const float* __restrict__ fw,
                                               const float* __restrict__ fb,
                                               const float* __restrict__ gsum,
                                               float* __restrict__ seq) {
  const int t = threadIdx.x;  // graph / seq row
  float xv[64];
  #pragma unroll
  for (int k = 0; k < 64; k++) xv[k] = x[t*64 + k];
  for (int j = 0; j < 28; j++) {
    float acc = fb[j];
    #pragma unroll
    for (int k = 0; k < 64; k++) acc += fw[j*64 + k] * xv[k];
    seq[t*32 + j] = fmaxf(acc, 0.f);
  }
  #pragma unroll
  for (int f = 0; f < 4; f++)
    seq[t*32 + 28 + f] = gsum[t*4 + f] * (1.0f / 4096.0f);
}

// ---------------- input-side gates, transposed: pg4[(step*256+rt)*4 + gate] ----------------
__global__ __launch_bounds__(256) void k_pregates(const float* __restrict__ Wih,
                                                  const float* __restrict__ bih,
                                                  const float* __restrict__ bhh,
                                                  const float* __restrict__ seq,
                                                  float* __restrict__ pg4) {
  const int b = blockIdx.x;
  const int step = b >> 2;
  const int gate = b & 3;
  const int rt = threadIdx.x;
  const int row = gate * 256 + rt;
  const float* sr = seq + step * 32;
  float acc = bih[row] + bhh[row];
  const float4* wr = (const float4*)(Wih + (size_t)row * 32);
  #pragma unroll
  for (int c = 0; c < 8; c++) {
    float4 w = wr[c];
    acc += w.x * sr[4*c+0] + w.y * sr[4*c+1] + w.z * sr[4*c+2] + w.w * sr[4*c+3];
  }
  pg4[((size_t)step * 256 + rt) * 4 + gate] = acc;
}

// ---------------- W_hh f32 -> f16 pairs, permuted for the 8-WG DPP-GEMV ----------------
// w16 flat uint index = wg*16384 + p*2048 + rd*1024 + t*4 + comp  (u = rd*4+comp):
//   = W_hh[row wg*32 + p*4 + r + 256*wv][f16 cols 2c,2c+1], c = g*8+u,
//   where wv=t>>6, r=(t>>4)&3, g=t&15.  (lane-consecutive uint4 -> conflict-floor b128)
__global__ __launch_bounds__(256) void k_w16(const float* __restrict__ Whh,
                                             unsigned int* __restrict__ w16) {
  const int pid = blockIdx.x * 256 + threadIdx.x;   // [0, 131072)
  const int wg = pid >> 14;
  const int rem = pid & 16383;
  const int p = rem >> 11;
  const int rd = (rem >> 10) & 1;
  const int t = (rem >> 2) & 255;
  const int comp = rem & 3;
  const int u = rd * 4 + comp;
  const int wv = t >> 6, r = (t >> 4) & 3, g = t & 15;
  const int R = wg * 32 + p * 4 + r + 256 * wv;
  const int c = g * 8 + u;
  float2 v = ((const float2*)Whh)[(size_t)R * 128 + c];
  __half2 h = __floats2half2_rn(v.x, v.y);
  w16[pid] = *(unsigned int*)&h;
}

// ---------------- LSTM: 8 cooperative WGs, tagged-h sync, wave0-poll broadcast ----------------
typedef _Float16 half2_t __attribute__((ext_vector_type(2)));

__device__ inline float dot2(unsigned int a, unsigned int b, float c) {
  return __builtin_amdgcn_fdot2(__builtin_bit_cast(half2_t, a),
                                __builtin_bit_cast(half2_t, b), c, false);
}

// sum across each 16-lane group via DPP row_shr (lane l%16==15 holds the sum)
__device__ inline float red16(float v) {
  int x;
  x = __builtin_amdgcn_update_dpp(0, __builtin_bit_cast(int, v), 0x111, 0xF, 0xF, false);
  v += __builtin_bit_cast(float, x);
  x = __builtin_amdgcn_update_dpp(0, __builtin_bit_cast(int, v), 0x112, 0xF, 0xF, false);
  v += __builtin_bit_cast(float, x);
  x = __builtin_amdgcn_update_dpp(0, __builtin_bit_cast(int, v), 0x114, 0xF, 0xF, false);
  v += __builtin_bit_cast(float, x);
  x = __builtin_amdgcn_update_dpp(0, __builtin_bit_cast(int, v), 0x118, 0xF, 0xF, false);
  v += __builtin_bit_cast(float, x);
  return v;
}

__device__ inline float fast_sig(float x) { return 1.f / (1.f + __expf(-x)); }
__device__ inline float fast_tanh(float x) {
  float xc = fminf(fmaxf(x, -30.f), 30.f);
  float e = __expf(2.f * xc);
  return (e - 1.f) / (e + 1.f);
}

// LDS: [0,64K) weights (4096 uint4) | [64K,64K+512) gex[128] | [64K+512, +1K) hbc[2][128]
// padded to 80K -> 1 WG/CU
#define L8_LDS_BYTES 81920

// WG wg (of 8), 256 thr = 4 waves. Wave wv owns gate wv, rows wg*32+[0,32).
// Lane l=r*16+g holds h-slice pairs [g*8,g*8+8). h exchange: tagged u64 words
// hbuf[slot=step&1][uint k] = (tag<<32)|data, tag = step this h is INPUT for
// (r7-verified protocol). NEW: only wave 0 polls (2 u64/lane + __all + s_sleep
// backoff) and broadcasts the 128 data words via LDS hbc — cuts the concurrent
// agent-atomic poll traffic ~16x (r7: all 2048 threads hammered 16 LLC lines).
__global__ __launch_bounds__(256) void k_lstm8(const unsigned int* __restrict__ w16,
                                               const float* __restrict__ pg4,
                                               unsigned long long* __restrict__ hbuf,
                                               float* __restrict__ out) {
  extern __shared__ char smem[];
  uint4* wl4 = (uint4*)smem;                           // [4096]
  float* gex = (float*)(smem + 65536);                 // [128]
  unsigned int* hbc = (unsigned int*)(smem + 66048);   // [2][128]
  const int wg = blockIdx.x;
  const int t = threadIdx.x;
  const int l = t & 63, g = l & 15;
  // stage this WG's 64KB weight slice (linear copy, coalesced both sides)
  const uint4* g4 = (const uint4*)(w16 + (size_t)wg * 16384);
  #pragma unroll
  for (int k = 0; k < 16; k++) wl4[t + k * 256] = g4[t + k * 256];
  float cs = 0.f;                         // c_state, live in t<32
  __syncthreads();
  const int gexi0 = (t & 3) * 8 + (t >> 2);   // nonlin gex base (valid t<32)
  for (int step = 0; step < 256; ++step) {
    const int par = step & 1;
    // prefetch pregates (independent of h) before the poll
    float4 pf;
    if (t < 32)
      pf = *(const float4*)(pg4 + ((size_t)step * 256 + wg * 32 + t) * 4);
    // wave 0: poll all 128 tagged words (2 per lane), then broadcast via LDS
    if (t < 64) {
      const unsigned long long* hb = hbuf + par * 128 + 2 * t;
      unsigned long long v0, v1;
      for (;;) {
        v0 = __hip_atomic_load(hb + 0, __ATOMIC_RELAXED, __HIP_MEMORY_SCOPE_AGENT);
        v1 = __hip_atomic_load(hb + 1, __ATOMIC_RELAXED, __HIP_MEMORY_SCOPE_AGENT);
        bool ok = ((unsigned)(v0 >> 32) == (unsigned)step) &&
                  ((unsigned)(v1 >> 32) == (unsigned)step);
        if (__all(ok)) break;
        __builtin_amdgcn_s_sleep(1);
      }
      *(uint2*)(hbc + par * 128 + 2 * t) =
          make_uint2((unsigned)v0, (unsigned)v1);
    }
    __syncthreads();   // barrier A: hbc[par] ready for all waves
    const uint4 va = *(const uint4*)(hbc + par * 128 + 8 * g);
    const uint4 vb = *(const uint4*)(hbc + par * 128 + 8 * g + 4);
    const unsigned int h0 = va.x, h1 = va.y, h2 = va.z, h3 = va.w;
    const unsigned int h4 = vb.x, h5 = vb.y, h6 = vb.z, h7 = vb.w;
    float res[4];
    #pragma unroll
    for (int p = 0; p < 8; ++p) {
      const uint4 w0 = wl4[p * 512 + t];
      const uint4 w1 = wl4[p * 512 + 256 + t];
      float s = 0.f;
      s = dot2(w0.x, h0, s);
      s = dot2(w0.y, h1, s);
      s = dot2(w0.z, h2, s);
      s = dot2(w0.w, h3, s);
      s = dot2(w1.x, h4, s);
      s = dot2(w1.y, h5, s);
      s = dot2(w1.z, h6, s);
      s = dot2(w1.w, h7, s);
      res[p & 3] = red16(s);
      if ((p & 3) == 3 && (l & 15) == 15)
        *(float4*)(gex + (t >> 6) * 32 + ((l >> 4) & 3) * 8 + (p - 3)) =
            make_float4(res[0], res[1], res[2], res[3]);
    }
    __syncthreads();   // barrier B: gex writes (all waves) -> gex reads (wave 0)
    if (t < 32) {
      float gi = gex[ 0 + gexi0] + pf.x;
      float gf = gex[32 + gexi0] + pf.y;
      float gg = gex[64 + gexi0] + pf.z;
      float go = gex[96 + gexi0] + pf.w;
      float si = fast_sig(gi);
      float sf = fast_sig(gf);
      float so = fast_sig(go);
      float tg = fast_tanh(gg);
      cs = sf * cs + si * tg;
      float hn = so * fast_tanh(cs);
      out[step * 256 + wg * 32 + t] = hn;
      float he = __shfl(hn, (t & 15) * 2);
      float ho = __shfl(hn, (t & 15) * 2 + 1);
      if (t < 16) {
        __half2 hp = __floats2half2_rn(he, ho);
        unsigned long long w =
            ((unsigned long long)(step + 1) << 32) | *(unsigned int*)&hp;
        __hip_atomic_store(hbuf + ((step + 1) & 1) * 128 + wg * 16 + t, w,
                           __ATOMIC_RELAXED, __HIP_MEMORY_SCOPE_AGENT);
      }
    }
    // no trailing barrier: cross-step hazards gated by the tag poll + barriers A/B
  }
}

extern "C" void kernel_launch(void* const* d_in, const int* in_sizes, int n_in,
                              void* d_out, int out_size, void* d_ws, size_t ws_size,
                              hipStream_t stream) {
  const float* x    = (const float*)d_in[0];
  const int*   esrc = (const int*)d_in[1];
  const int*   edst = (const int*)d_in[2];
  // d_in[3] node_graph_ids: implied by node index (n >> 12)
  const float* fc1w = (const float*)d_in[4];
  const float* fc1b = (const float*)d_in[5];
  const float* g1w  = (const float*)d_in[6];
  const float* g1b  = (const float*)d_in[7];
  const float* g2w  = (const float*)d_in[8];
  const float* g2b  = (const float*)d_in[9];
  const float* g3w  = (const float*)d_in[10];
  const float* g3b  = (const float*)d_in[11];
  const float* Wih  = (const float*)d_in[12];
  const float* Whh  = (const float*)d_in[13];
  const float* bih  = (const float*)d_in[14];
  const float* bhh  = (const float*)d_in[15];
  // d_in[16], d_in[17]: w_omega/u_omega — result discarded by reference

  float* ws = (float*)d_ws;
  int*            off  = (int*)(ws + W_OFF);
  float*          deg2 = ws + W_DEG2;
  unsigned short* srt  = (unsigned short*)(ws + W_SRT);
  float*          ha   = ws + W_HA;
  float*          hb   = ws + W_HB;
  float*          gsum = ws + W_GSUM;
  float*          seq  = ws + W_SEQ;
  float*          pg4  = ws + W_PG;
  unsigned int*   w16  = (unsigned int*)(ws + W_W16);
  unsigned long long* hbuf = (unsigned long long*)(ws + W_SYNC);  // [2][128] tagged

  hipMemsetAsync(gsum, 0, 1024 * 4, stream);
  hipMemsetAsync(hbuf, 0, 2 * 128 * 8, stream);   // (tag0, h0=0) both slots
  k_sort<<<256, 1024, SORT_LDS_BYTES, stream>>>(esrc, edst, off, (float2*)deg2, srt,
                                                g1w, g1b, ha);
  k_w16<<<512, 256, 0, stream>>>(Whh, w16);
  k_conv<12, 12, false><<<4096, 256, 0, stream>>>(off, srt, ha, g2w, g2b, hb, nullptr);
  k_conv<12, 4, true ><<<4096, 256, 0, stream>>>(off, srt, hb, g3w, g3b, nullptr, gsum);
  k_small<<<1, 256, 0, stream>>>(x, fc1w, fc1b, gsum, seq);
  k_pregates<<<1024, 256, 0, stream>>>(Wih, bih, bhh, seq, pg4);
  k_lstm8<<<8, 256, L8_LDS_BYTES, stream>>>(w16, pg4, hbuf, (float*)d_out);
}